// Round 1
// baseline (1327.584 us; speedup 1.0000x reference)
//
#include <hip/hip_runtime.h>

#define N_NODES 50000
#define N_EDGES 800000
#define DIM 128
#define H 8

// Monotone float<->ordered-int transform (involution) so atomicMax(int*) == float max.
__device__ __forceinline__ int ford(float f) {
    int i = __float_as_int(f);
    return (i >= 0) ? i : (i ^ 0x7FFFFFFF);
}
__device__ __forceinline__ float iord(int i) {
    return __int_as_float((i >= 0) ? i : (i ^ 0x7FFFFFFF));
}

// Kernel A: LayerNorm + x@W_in + b_in, then scores_u = y@W_u + b_u, scores_v = y@W_v.
// One node per 128-thread block.
__global__ __launch_bounds__(128) void k_ln_gemm(
    const float* __restrict__ x, const float* __restrict__ gamma, const float* __restrict__ beta,
    const float* __restrict__ W_in, const float* __restrict__ b_in,
    const float* __restrict__ W_u, const float* __restrict__ b_u, const float* __restrict__ W_v,
    float* __restrict__ y, float* __restrict__ su, float* __restrict__ sv)
{
    int n = blockIdx.x, t = threadIdx.x;
    __shared__ float xs[DIM];
    __shared__ float red[DIM];

    float xv = x[n * DIM + t];

    // mean
    red[t] = xv; __syncthreads();
    for (int s = 64; s > 0; s >>= 1) { if (t < s) red[t] += red[t + s]; __syncthreads(); }
    float mu = red[0] * (1.0f / DIM);
    __syncthreads();

    // variance (two-pass, matches reference)
    float d = xv - mu;
    red[t] = d * d; __syncthreads();
    for (int s = 64; s > 0; s >>= 1) { if (t < s) red[t] += red[t + s]; __syncthreads(); }
    float var = red[0] * (1.0f / DIM);
    __syncthreads();

    float xn = d * rsqrtf(var + 1e-5f) * gamma[t] + beta[t];
    xs[t] = xn; __syncthreads();

    // y[n, t] = b_in[t] + sum_k xs[k] * W_in[k, t]
    float acc = b_in[t];
    #pragma unroll 8
    for (int k = 0; k < DIM; ++k) acc += xs[k] * W_in[k * DIM + t];
    y[n * DIM + t] = acc;

    __syncthreads();
    xs[t] = acc;
    __syncthreads();

    // scores: 16 tasks (8 for su, 8 for sv), each split over 8 threads of 16 elems
    int task = t >> 3;   // 0..15
    int seg  = t & 7;    // 0..7
    int h    = task & 7;
    const float* W = (task < 8) ? W_u : W_v;
    float a = 0.f;
    int c0 = seg * 16;
    #pragma unroll
    for (int c = 0; c < 16; ++c) a += xs[c0 + c] * W[(c0 + c) * H + h];
    red[t] = a;
    __syncthreads();
    if (seg == 0) {
        float s2 = red[t] + red[t+1] + red[t+2] + red[t+3]
                 + red[t+4] + red[t+5] + red[t+6] + red[t+7];
        if (task < 8) su[n * H + h] = s2 + b_u[h];
        else          sv[n * H + h] = s2;
    }
}

// Init: m_ord = ford(-inf), s_sum = 0, agg = 0 (ws is poisoned 0xAA before each call)
__global__ __launch_bounds__(256) void k_init(int* __restrict__ m_ord, float* __restrict__ s_sum,
                                              float* __restrict__ agg)
{
    int i = blockIdx.x * blockDim.x + threadIdx.x;
    if (i < N_NODES * H) { m_ord[i] = 0x807FFFFF; s_sum[i] = 0.f; }  // 0x807FFFFF == ford(-inf)
    if (i < N_NODES * DIM) agg[i] = 0.f;
}

// Edge pass 1: segment max of leakyrelu(su[src]+sv[dst]) over dst
__global__ __launch_bounds__(256) void k_edge_max(
    const int* __restrict__ src, const int* __restrict__ dst,
    const float* __restrict__ su, const float* __restrict__ sv, int* __restrict__ m_ord)
{
    int e = blockIdx.x * blockDim.x + threadIdx.x;
    if (e >= N_EDGES) return;
    int s8 = src[e] * H, d8 = dst[e] * H;
    #pragma unroll
    for (int h = 0; h < H; ++h) {
        float v = su[s8 + h] + sv[d8 + h];
        v = (v >= 0.f) ? v : 0.2f * v;
        atomicMax(&m_ord[d8 + h], ford(v));
    }
}

// Edge pass 2: segment sum of exp(e - m[dst])
__global__ __launch_bounds__(256) void k_edge_sum(
    const int* __restrict__ src, const int* __restrict__ dst,
    const float* __restrict__ su, const float* __restrict__ sv,
    const int* __restrict__ m_ord, float* __restrict__ s_sum)
{
    int e = blockIdx.x * blockDim.x + threadIdx.x;
    if (e >= N_EDGES) return;
    int s8 = src[e] * H, d8 = dst[e] * H;
    #pragma unroll
    for (int h = 0; h < H; ++h) {
        float v = su[s8 + h] + sv[d8 + h];
        v = (v >= 0.f) ? v : 0.2f * v;
        float m = iord(m_ord[d8 + h]);
        atomicAdd(&s_sum[d8 + h], expf(v - m));
    }
}

// Edge pass 3: agg[dst, f] += y[src, f] * prob[e, f%8]
// One thread per (edge, feature). feature f belongs to head f%8 (reshape (N, hd, H)).
__global__ __launch_bounds__(256) void k_edge_agg(
    const int* __restrict__ src, const int* __restrict__ dst,
    const float* __restrict__ su, const float* __restrict__ sv,
    const int* __restrict__ m_ord, const float* __restrict__ s_sum,
    const float* __restrict__ y, float* __restrict__ agg)
{
    long long idx = (long long)blockIdx.x * blockDim.x + threadIdx.x;
    if (idx >= (long long)N_EDGES * DIM) return;
    int e = (int)(idx >> 7);
    int f = (int)(idx & 127);
    int h = f & 7;
    int sn = src[e], dn = dst[e];
    float v = su[sn * H + h] + sv[dn * H + h];
    v = (v >= 0.f) ? v : 0.2f * v;
    float m = iord(m_ord[dn * H + h]);
    float p = expf(v - m) / s_sum[dn * H + h];
    atomicAdd(&agg[dn * DIM + f], y[sn * DIM + f] * p);
}

// Output GEMM: out = agg @ W_ff + b_ff, one node per 128-thread block
__global__ __launch_bounds__(128) void k_gemm_out(
    const float* __restrict__ agg, const float* __restrict__ W_ff,
    const float* __restrict__ b_ff, float* __restrict__ out)
{
    int n = blockIdx.x, t = threadIdx.x;
    __shared__ float xs[DIM];
    xs[t] = agg[n * DIM + t];
    __syncthreads();
    float acc = b_ff[t];
    #pragma unroll 8
    for (int k = 0; k < DIM; ++k) acc += xs[k] * W_ff[k * DIM + t];
    out[n * DIM + t] = acc;
}

extern "C" void kernel_launch(void* const* d_in, const int* in_sizes, int n_in,
                              void* d_out, int out_size, void* d_ws, size_t ws_size,
                              hipStream_t stream)
{
    const float* x     = (const float*)d_in[0];
    const int*   src   = (const int*)  d_in[1];
    const int*   dst   = (const int*)  d_in[2];
    const float* gamma = (const float*)d_in[3];
    const float* beta  = (const float*)d_in[4];
    const float* W_in  = (const float*)d_in[5];
    const float* b_in  = (const float*)d_in[6];
    const float* W_u   = (const float*)d_in[7];
    const float* b_u   = (const float*)d_in[8];
    const float* W_v   = (const float*)d_in[9];
    const float* W_ff  = (const float*)d_in[10];
    const float* b_ff  = (const float*)d_in[11];
    float* out = (float*)d_out;

    char* ws = (char*)d_ws;
    float* y     = (float*)ws; ws += (size_t)N_NODES * DIM * 4;
    float* su    = (float*)ws; ws += (size_t)N_NODES * H * 4;
    float* sv    = (float*)ws; ws += (size_t)N_NODES * H * 4;
    int*   m_ord = (int*)  ws; ws += (size_t)N_NODES * H * 4;
    float* s_sum = (float*)ws; ws += (size_t)N_NODES * H * 4;
    float* agg   = (float*)ws; ws += (size_t)N_NODES * DIM * 4;

    hipLaunchKernelGGL(k_init, dim3((N_NODES * DIM + 255) / 256), dim3(256), 0, stream,
                       m_ord, s_sum, agg);
    hipLaunchKernelGGL(k_ln_gemm, dim3(N_NODES), dim3(128), 0, stream,
                       x, gamma, beta, W_in, b_in, W_u, b_u, W_v, y, su, sv);
    hipLaunchKernelGGL(k_edge_max, dim3((N_EDGES + 255) / 256), dim3(256), 0, stream,
                       src, dst, su, sv, m_ord);
    hipLaunchKernelGGL(k_edge_sum, dim3((N_EDGES + 255) / 256), dim3(256), 0, stream,
                       src, dst, su, sv, m_ord, s_sum);
    hipLaunchKernelGGL(k_edge_agg, dim3((int)(((long long)N_EDGES * DIM) / 256)), dim3(256), 0, stream,
                       src, dst, su, sv, m_ord, s_sum, y, agg);
    hipLaunchKernelGGL(k_gemm_out, dim3(N_NODES), dim3(128), 0, stream,
                       agg, W_ff, b_ff, out);
}

// Round 2
// 359.100 us; speedup vs baseline: 3.6970x; 3.6970x over previous
//
#include <hip/hip_runtime.h>

#define N_NODES 50000
#define N_EDGES 800000
#define DIM 128
#define H 8

// ---------------------------------------------------------------------------
// Fused LN + 128x128 GEMM (and plain GEMM for the output FF).
// Block: 256 threads, 64 nodes. W staged in LDS in 64x64 chunks (16 KB),
// input tile transposed in LDS (stride 68 keeps float4 alignment + banks ok).
// Each thread: 4 nodes x 4 cols register tile, ds_read_b128 operands.
// ---------------------------------------------------------------------------
template<bool DO_LN>
__global__ __launch_bounds__(256) void k_gemm128(
    const float* __restrict__ X, const float* __restrict__ W,
    const float* __restrict__ bias,
    const float* __restrict__ gamma, const float* __restrict__ beta,
    float* __restrict__ Y)
{
    __shared__ float xsT[128 * 68];  // [k][n] transposed, row stride 68
    __shared__ float Wc[64 * 64];    // one 64k x 64c chunk of W

    const int t = threadIdx.x;
    const int n0 = blockIdx.x * 64;

    // ---- Phase 1: load 64 nodes x 128 feats, optional LayerNorm, transpose
    {
        const int nl = t >> 2;          // local node 0..63
        const int q  = t & 3;           // feature quarter
        int n = n0 + nl;
        int nc = (n < N_NODES) ? n : 0; // clamp tail (results never stored)
        const float4* xr = (const float4*)(X + (size_t)nc * DIM + q * 32);
        float4 v[8];
        #pragma unroll
        for (int u = 0; u < 8; ++u) v[u] = xr[u];

        if (DO_LN) {
            float s = 0.f, ss = 0.f;
            #pragma unroll
            for (int u = 0; u < 8; ++u) {
                s  += v[u].x + v[u].y + v[u].z + v[u].w;
                ss += v[u].x*v[u].x + v[u].y*v[u].y + v[u].z*v[u].z + v[u].w*v[u].w;
            }
            s  += __shfl_xor(s, 1);  s  += __shfl_xor(s, 2);
            ss += __shfl_xor(ss, 1); ss += __shfl_xor(ss, 2);
            float mu  = s * (1.f / DIM);
            float var = ss * (1.f / DIM) - mu * mu;
            float rstd = rsqrtf(var + 1e-5f);
            const float4* g4 = (const float4*)(gamma + q * 32);
            const float4* b4 = (const float4*)(beta  + q * 32);
            #pragma unroll
            for (int u = 0; u < 8; ++u) {
                float4 gg = g4[u], bb = b4[u];
                v[u].x = (v[u].x - mu) * rstd * gg.x + bb.x;
                v[u].y = (v[u].y - mu) * rstd * gg.y + bb.y;
                v[u].z = (v[u].z - mu) * rstd * gg.z + bb.z;
                v[u].w = (v[u].w - mu) * rstd * gg.w + bb.w;
            }
        }
        #pragma unroll
        for (int u = 0; u < 8; ++u) {
            int f = q * 32 + u * 4;
            xsT[(f+0)*68 + nl] = v[u].x;
            xsT[(f+1)*68 + nl] = v[u].y;
            xsT[(f+2)*68 + nl] = v[u].z;
            xsT[(f+3)*68 + nl] = v[u].w;
        }
    }

    const int nj = t >> 4;   // 0..15 -> nodes 4nj..4nj+3
    const int cj = t & 15;   // 0..15 -> cols 4cj..4cj+3 (within 64-col pass)

    #pragma unroll
    for (int p = 0; p < 2; ++p) {          // column halves
        float acc[16];
        #pragma unroll
        for (int i = 0; i < 16; ++i) acc[i] = 0.f;

        for (int kc = 0; kc < 2; ++kc) {   // k halves
            __syncthreads();               // xsT ready (1st) / Wc reads done
            #pragma unroll
            for (int it = 0; it < 4; ++it) {
                int id = it * 256 + t;     // 0..1023
                int k  = id >> 4;
                int c4 = id & 15;
                float4 w = *(const float4*)(W + (size_t)(kc*64 + k) * DIM + p*64 + c4*4);
                *(float4*)(Wc + k*64 + c4*4) = w;
            }
            __syncthreads();
            #pragma unroll 8
            for (int k = 0; k < 64; ++k) {
                float4 a = *(const float4*)(xsT + (kc*64 + k)*68 + (nj<<2));
                float4 b = *(const float4*)(Wc  + (k<<6) + (cj<<2));
                acc[ 0] += a.x*b.x; acc[ 1] += a.x*b.y; acc[ 2] += a.x*b.z; acc[ 3] += a.x*b.w;
                acc[ 4] += a.y*b.x; acc[ 5] += a.y*b.y; acc[ 6] += a.y*b.z; acc[ 7] += a.y*b.w;
                acc[ 8] += a.z*b.x; acc[ 9] += a.z*b.y; acc[10] += a.z*b.z; acc[11] += a.z*b.w;
                acc[12] += a.w*b.x; acc[13] += a.w*b.y; acc[14] += a.w*b.z; acc[15] += a.w*b.w;
            }
        }
        float4 bb = *(const float4*)(bias + p*64 + (cj<<2));
        #pragma unroll
        for (int i = 0; i < 4; ++i) {
            int n = n0 + (nj<<2) + i;
            if (n < N_NODES) {
                float4 o;
                o.x = acc[i*4+0] + bb.x;
                o.y = acc[i*4+1] + bb.y;
                o.z = acc[i*4+2] + bb.z;
                o.w = acc[i*4+3] + bb.w;
                *(float4*)(Y + (size_t)n * DIM + p*64 + (cj<<2)) = o;
            }
        }
    }
}

// ---------------------------------------------------------------------------
// Scores: su = y@W_u + b_u, sv = y@W_v. One wave per node (4 nodes/block).
// ---------------------------------------------------------------------------
__global__ __launch_bounds__(256) void k_scores(
    const float* __restrict__ y, const float* __restrict__ W_u,
    const float* __restrict__ b_u, const float* __restrict__ W_v,
    float* __restrict__ su, float* __restrict__ sv)
{
    __shared__ float ys[4][DIM];
    const int w = threadIdx.x >> 6, l = threadIdx.x & 63;
    const int n = blockIdx.x * 4 + w;   // grid = 12500 -> exact

    float2 yy = *(const float2*)(y + (size_t)n * DIM + l * 2);
    ys[w][l*2]     = yy.x;
    ys[w][l*2 + 1] = yy.y;
    __syncthreads();

    const int o   = l & 15;   // 0..7: su head, 8..15: sv head
    const int seg = l >> 4;   // k-quarter
    const int h   = o & 7;
    const float* Wm = (o < 8) ? W_u : W_v;
    float sum = 0.f;
    #pragma unroll
    for (int j = 0; j < 32; ++j)
        sum += ys[w][seg*32 + j] * Wm[(seg*32 + j) * H + h];
    sum += __shfl_xor(sum, 16);
    sum += __shfl_xor(sum, 32);
    if (l < 16) {
        if (o < 8) su[n*H + o]       = sum + b_u[o];
        else       sv[n*H + (o - 8)] = sum;
    }
}

// ---------------------------------------------------------------------------
// CSR build: zero, histogram, 2-level scan, scatter
// ---------------------------------------------------------------------------
__global__ __launch_bounds__(256) void k_zero(int* __restrict__ deg, int* __restrict__ cur)
{
    int i = blockIdx.x * 256 + threadIdx.x;
    if (i < N_NODES) { deg[i] = 0; cur[i] = 0; }
}

__global__ __launch_bounds__(256) void k_hist(const int* __restrict__ dst, int* __restrict__ deg)
{
    int e = blockIdx.x * 256 + threadIdx.x;
    if (e < N_EDGES) atomicAdd(&deg[dst[e]], 1);
}

__global__ __launch_bounds__(256) void k_scan1(const int* __restrict__ deg,
                                               int* __restrict__ incl, int* __restrict__ bsum)
{
    __shared__ int s[256];
    int t = threadIdx.x;
    int i = blockIdx.x * 256 + t;
    s[t] = (i < N_NODES) ? deg[i] : 0;
    __syncthreads();
    for (int off = 1; off < 256; off <<= 1) {
        int x = (t >= off) ? s[t - off] : 0;
        __syncthreads();
        s[t] += x;
        __syncthreads();
    }
    if (i < N_NODES) incl[i] = s[t];
    if (t == 255) bsum[blockIdx.x] = s[255];
}

__global__ __launch_bounds__(256) void k_scan2(int* __restrict__ bsum, int nb)
{
    __shared__ int s[256];
    int t = threadIdx.x;
    s[t] = (t < nb) ? bsum[t] : 0;
    __syncthreads();
    for (int off = 1; off < 256; off <<= 1) {
        int x = (t >= off) ? s[t - off] : 0;
        __syncthreads();
        s[t] += x;
        __syncthreads();
    }
    if (t < nb) bsum[t] = s[t];
}

__global__ __launch_bounds__(256) void k_scan3(const int* __restrict__ deg,
                                               const int* __restrict__ incl,
                                               const int* __restrict__ bsum,
                                               int* __restrict__ row_start)
{
    int i = blockIdx.x * 256 + threadIdx.x;
    if (i < N_NODES) {
        int boff = (blockIdx.x > 0) ? bsum[blockIdx.x - 1] : 0;
        row_start[i] = incl[i] - deg[i] + boff;
    }
}

__global__ __launch_bounds__(256) void k_scatter(const int* __restrict__ src,
                                                 const int* __restrict__ dst,
                                                 const int* __restrict__ row_start,
                                                 int* __restrict__ cur, int* __restrict__ esrc)
{
    int e = blockIdx.x * 256 + threadIdx.x;
    if (e < N_EDGES) {
        int d = dst[e];
        int pos = row_start[d] + atomicAdd(&cur[d], 1);
        esrc[pos] = src[e];
    }
}

// ---------------------------------------------------------------------------
// Softmax + aggregation: one wave per dst node, no atomics.
// Lane l owns features l and l+64 (both head l&7 since 64%8==0).
// ---------------------------------------------------------------------------
__global__ __launch_bounds__(64) void k_node_agg(
    const int* __restrict__ esrc, const int* __restrict__ row_start,
    const int* __restrict__ deg,
    const float* __restrict__ su, const float* __restrict__ sv,
    const float* __restrict__ y, float* __restrict__ agg)
{
    const int n = blockIdx.x, l = threadIdx.x;
    const int start = row_start[n], d = deg[n];

    float svv[8];
    {
        float4 a = *(const float4*)(sv + n*H);
        float4 b = *(const float4*)(sv + n*H + 4);
        svv[0]=a.x; svv[1]=a.y; svv[2]=a.z; svv[3]=a.w;
        svv[4]=b.x; svv[5]=b.y; svv[6]=b.z; svv[7]=b.w;
    }

    // Phase A: per-head max
    float m[8];
    #pragma unroll
    for (int h = 0; h < 8; ++h) m[h] = -INFINITY;
    for (int i = l; i < d; i += 64) {
        int s = esrc[start + i];
        float4 a = *(const float4*)(su + s*H);
        float4 b = *(const float4*)(su + s*H + 4);
        float s8[8] = {a.x,a.y,a.z,a.w,b.x,b.y,b.z,b.w};
        #pragma unroll
        for (int h = 0; h < 8; ++h) {
            float e = s8[h] + svv[h];
            e = (e >= 0.f) ? e : 0.2f * e;
            m[h] = fmaxf(m[h], e);
        }
    }
    #pragma unroll
    for (int h = 0; h < 8; ++h) {
        #pragma unroll
        for (int o = 1; o < 64; o <<= 1) m[h] = fmaxf(m[h], __shfl_xor(m[h], o));
    }

    // Phase B: per-head sum of exp
    float ssum[8];
    #pragma unroll
    for (int h = 0; h < 8; ++h) ssum[h] = 0.f;
    for (int i = l; i < d; i += 64) {
        int s = esrc[start + i];
        float4 a = *(const float4*)(su + s*H);
        float4 b = *(const float4*)(su + s*H + 4);
        float s8[8] = {a.x,a.y,a.z,a.w,b.x,b.y,b.z,b.w};
        #pragma unroll
        for (int h = 0; h < 8; ++h) {
            float e = s8[h] + svv[h];
            e = (e >= 0.f) ? e : 0.2f * e;
            ssum[h] += __expf(e - m[h]);
        }
    }
    #pragma unroll
    for (int h = 0; h < 8; ++h) {
        #pragma unroll
        for (int o = 1; o < 64; o <<= 1) ssum[h] += __shfl_xor(ssum[h], o);
    }

    // Phase C: weighted aggregation
    const int h0 = l & 7;
    const float mh = m[h0], svh = svv[h0];
    const float rsh = 1.f / ssum[h0];
    float acc0 = 0.f, acc1 = 0.f;
    for (int i = 0; i < d; ++i) {
        int s = esrc[start + i];
        float e = su[s*H + h0] + svh;
        e = (e >= 0.f) ? e : 0.2f * e;
        float p = __expf(e - mh) * rsh;
        acc0 += y[(size_t)s*DIM + l]      * p;
        acc1 += y[(size_t)s*DIM + 64 + l] * p;
    }
    agg[(size_t)n*DIM + l]      = acc0;
    agg[(size_t)n*DIM + 64 + l] = acc1;
}

// ---------------------------------------------------------------------------
extern "C" void kernel_launch(void* const* d_in, const int* in_sizes, int n_in,
                              void* d_out, int out_size, void* d_ws, size_t ws_size,
                              hipStream_t stream)
{
    const float* x     = (const float*)d_in[0];
    const int*   src   = (const int*)  d_in[1];
    const int*   dst   = (const int*)  d_in[2];
    const float* gamma = (const float*)d_in[3];
    const float* beta  = (const float*)d_in[4];
    const float* W_in  = (const float*)d_in[5];
    const float* b_in  = (const float*)d_in[6];
    const float* W_u   = (const float*)d_in[7];
    const float* b_u   = (const float*)d_in[8];
    const float* W_v   = (const float*)d_in[9];
    const float* W_ff  = (const float*)d_in[10];
    const float* b_ff  = (const float*)d_in[11];
    float* out = (float*)d_out;

    char* ws = (char*)d_ws;
    float* y         = (float*)ws; ws += (size_t)N_NODES * DIM * 4;
    float* agg       = (float*)ws; ws += (size_t)N_NODES * DIM * 4;
    float* su        = (float*)ws; ws += (size_t)N_NODES * H * 4;
    float* sv        = (float*)ws; ws += (size_t)N_NODES * H * 4;
    int*   deg       = (int*)  ws; ws += (size_t)N_NODES * 4;
    int*   cur       = (int*)  ws; ws += (size_t)N_NODES * 4;
    int*   incl      = (int*)  ws; ws += (size_t)N_NODES * 4;
    int*   row_start = (int*)  ws; ws += (size_t)N_NODES * 4;
    int*   bsum      = (int*)  ws; ws += 1024;
    int*   esrc      = (int*)  ws; ws += (size_t)N_EDGES * 4;

    const int NB_NODE = (N_NODES + 255) / 256;   // 196
    const int NB_EDGE = (N_EDGES + 255) / 256;   // 3125
    const int NB_GEMM = (N_NODES + 63) / 64;     // 782

    hipLaunchKernelGGL(k_zero, dim3(NB_NODE), dim3(256), 0, stream, deg, cur);
    hipLaunchKernelGGL((k_gemm128<true>), dim3(NB_GEMM), dim3(256), 0, stream,
                       x, W_in, b_in, gamma, beta, y);
    hipLaunchKernelGGL(k_scores, dim3(N_NODES / 4), dim3(256), 0, stream,
                       y, W_u, b_u, W_v, su, sv);
    hipLaunchKernelGGL(k_hist, dim3(NB_EDGE), dim3(256), 0, stream, dst, deg);
    hipLaunchKernelGGL(k_scan1, dim3(NB_NODE), dim3(256), 0, stream, deg, incl, bsum);
    hipLaunchKernelGGL(k_scan2, dim3(1), dim3(256), 0, stream, bsum, NB_NODE);
    hipLaunchKernelGGL(k_scan3, dim3(NB_NODE), dim3(256), 0, stream, deg, incl, bsum, row_start);
    hipLaunchKernelGGL(k_scatter, dim3(NB_EDGE), dim3(256), 0, stream,
                       src, dst, row_start, cur, esrc);
    hipLaunchKernelGGL(k_node_agg, dim3(N_NODES), dim3(64), 0, stream,
                       esrc, row_start, deg, su, sv, y, agg);
    hipLaunchKernelGGL((k_gemm128<false>), dim3(NB_GEMM), dim3(256), 0, stream,
                       agg, W_ff, b_ff, nullptr, nullptr, out);
}

// Round 4
// 309.746 us; speedup vs baseline: 4.2860x; 1.1593x over previous
//
#include <hip/hip_runtime.h>

#define N_NODES 50000
#define N_EDGES 800000
#define DIM 128
#define H 8

typedef unsigned short ushort_t;
typedef unsigned int uint_t;

__device__ __forceinline__ float bf2f(ushort_t u) {
    return __uint_as_float(((uint_t)u) << 16);
}
__device__ __forceinline__ ushort_t f2bf(float f) {
    uint_t x = __float_as_uint(f);
    uint_t r = (x + 0x7FFFu + ((x >> 16) & 1u)) >> 16;   // RNE
    return (ushort_t)r;
}

// ---------------------------------------------------------------------------
// Fused LN + 128x128 GEMM. Block: 256 threads, 64 nodes. W staged in LDS in
// 64x64 chunks, input tile transposed in LDS (stride 68). 4x4 register tiles.
// BF16_OUT: write bf16 (the y path); else fp32 (the final output path).
// ---------------------------------------------------------------------------
template<bool DO_LN, bool BF16_OUT>
__global__ __launch_bounds__(256) void k_gemm128(
    const float* __restrict__ X, const float* __restrict__ W,
    const float* __restrict__ bias,
    const float* __restrict__ gamma, const float* __restrict__ beta,
    float* __restrict__ Yf, ushort_t* __restrict__ Yb)
{
    __shared__ float xsT[128 * 68];  // [k][n] transposed, row stride 68
    __shared__ float Wc[64 * 64];    // one 64k x 64c chunk of W

    const int t = threadIdx.x;
    const int n0 = blockIdx.x * 64;

    // ---- Phase 1: load 64 nodes x 128 feats, optional LayerNorm, transpose
    {
        const int nl = t >> 2;          // local node 0..63
        const int q  = t & 3;           // feature quarter
        int n = n0 + nl;
        int nc = (n < N_NODES) ? n : 0; // clamp tail (results never stored)
        const float4* xr = (const float4*)(X + (size_t)nc * DIM + q * 32);
        float4 v[8];
        #pragma unroll
        for (int u = 0; u < 8; ++u) v[u] = xr[u];

        if (DO_LN) {
            float s = 0.f, ss = 0.f;
            #pragma unroll
            for (int u = 0; u < 8; ++u) {
                s  += v[u].x + v[u].y + v[u].z + v[u].w;
                ss += v[u].x*v[u].x + v[u].y*v[u].y + v[u].z*v[u].z + v[u].w*v[u].w;
            }
            s  += __shfl_xor(s, 1);  s  += __shfl_xor(s, 2);
            ss += __shfl_xor(ss, 1); ss += __shfl_xor(ss, 2);
            float mu  = s * (1.f / DIM);
            float var = ss * (1.f / DIM) - mu * mu;
            float rstd = rsqrtf(var + 1e-5f);
            const float4* g4 = (const float4*)(gamma + q * 32);
            const float4* b4 = (const float4*)(beta  + q * 32);
            #pragma unroll
            for (int u = 0; u < 8; ++u) {
                float4 gg = g4[u], bb = b4[u];
                v[u].x = (v[u].x - mu) * rstd * gg.x + bb.x;
                v[u].y = (v[u].y - mu) * rstd * gg.y + bb.y;
                v[u].z = (v[u].z - mu) * rstd * gg.z + bb.z;
                v[u].w = (v[u].w - mu) * rstd * gg.w + bb.w;
            }
        }
        #pragma unroll
        for (int u = 0; u < 8; ++u) {
            int f = q * 32 + u * 4;
            xsT[(f+0)*68 + nl] = v[u].x;
            xsT[(f+1)*68 + nl] = v[u].y;
            xsT[(f+2)*68 + nl] = v[u].z;
            xsT[(f+3)*68 + nl] = v[u].w;
        }
    }

    const int nj = t >> 4;   // 0..15 -> nodes 4nj..4nj+3
    const int cj = t & 15;   // 0..15 -> cols 4cj..4cj+3 (within 64-col pass)

    #pragma unroll
    for (int p = 0; p < 2; ++p) {          // column halves
        float acc[16];
        #pragma unroll
        for (int i = 0; i < 16; ++i) acc[i] = 0.f;

        for (int kc = 0; kc < 2; ++kc) {   // k halves
            __syncthreads();               // xsT ready (1st) / Wc reads done
            #pragma unroll
            for (int it = 0; it < 4; ++it) {
                int id = it * 256 + t;     // 0..1023
                int k  = id >> 4;
                int c4 = id & 15;
                float4 w = *(const float4*)(W + (size_t)(kc*64 + k) * DIM + p*64 + c4*4);
                *(float4*)(Wc + k*64 + c4*4) = w;
            }
            __syncthreads();
            #pragma unroll 8
            for (int k = 0; k < 64; ++k) {
                float4 a = *(const float4*)(xsT + (kc*64 + k)*68 + (nj<<2));
                float4 b = *(const float4*)(Wc  + (k<<6) + (cj<<2));
                acc[ 0] += a.x*b.x; acc[ 1] += a.x*b.y; acc[ 2] += a.x*b.z; acc[ 3] += a.x*b.w;
                acc[ 4] += a.y*b.x; acc[ 5] += a.y*b.y; acc[ 6] += a.y*b.z; acc[ 7] += a.y*b.w;
                acc[ 8] += a.z*b.x; acc[ 9] += a.z*b.y; acc[10] += a.z*b.z; acc[11] += a.z*b.w;
                acc[12] += a.w*b.x; acc[13] += a.w*b.y; acc[14] += a.w*b.z; acc[15] += a.w*b.w;
            }
        }
        float4 bb = *(const float4*)(bias + p*64 + (cj<<2));
        #pragma unroll
        for (int i = 0; i < 4; ++i) {
            int n = n0 + (nj<<2) + i;
            if (n < N_NODES) {
                float ox = acc[i*4+0] + bb.x;
                float oy = acc[i*4+1] + bb.y;
                float oz = acc[i*4+2] + bb.z;
                float ow = acc[i*4+3] + bb.w;
                if (BF16_OUT) {
                    ushort4 o;
                    o.x = f2bf(ox); o.y = f2bf(oy); o.z = f2bf(oz); o.w = f2bf(ow);
                    *(ushort4*)(Yb + (size_t)n * DIM + p*64 + (cj<<2)) = o;
                } else {
                    float4 o = make_float4(ox, oy, oz, ow);
                    *(float4*)(Yf + (size_t)n * DIM + p*64 + (cj<<2)) = o;
                }
            }
        }
    }
}

// ---------------------------------------------------------------------------
// Scores from bf16 y: su = y@W_u + b_u, sv = y@W_v. One wave per node.
// ---------------------------------------------------------------------------
__global__ __launch_bounds__(256) void k_scores(
    const ushort_t* __restrict__ yb, const float* __restrict__ W_u,
    const float* __restrict__ b_u, const float* __restrict__ W_v,
    float* __restrict__ su, float* __restrict__ sv)
{
    __shared__ float ys[4][DIM];
    const int w = threadIdx.x >> 6, l = threadIdx.x & 63;
    const int n = blockIdx.x * 4 + w;   // grid = 12500 -> exact

    ushort2 yy = ((const ushort2*)(yb + (size_t)n * DIM))[l];
    ys[w][l*2]     = bf2f(yy.x);
    ys[w][l*2 + 1] = bf2f(yy.y);
    __syncthreads();

    const int o   = l & 15;   // 0..7: su head, 8..15: sv head
    const int seg = l >> 4;   // k-quarter
    const int h   = o & 7;
    const float* Wm = (o < 8) ? W_u : W_v;
    float sum = 0.f;
    #pragma unroll
    for (int j = 0; j < 32; ++j)
        sum += ys[w][seg*32 + j] * Wm[(seg*32 + j) * H + h];
    sum += __shfl_xor(sum, 16);
    sum += __shfl_xor(sum, 32);
    if (l < 16) {
        if (o < 8) su[n*H + o]       = sum + b_u[o];
        else       sv[n*H + (o - 8)] = sum;
    }
}

// ---------------------------------------------------------------------------
// CSR build: zero, histogram, 2-level scan, scatter
// ---------------------------------------------------------------------------
__global__ __launch_bounds__(256) void k_zero(int* __restrict__ deg, int* __restrict__ cur)
{
    int i = blockIdx.x * 256 + threadIdx.x;
    if (i < N_NODES) { deg[i] = 0; cur[i] = 0; }
}

__global__ __launch_bounds__(256) void k_hist(const int* __restrict__ dst, int* __restrict__ deg)
{
    int e = blockIdx.x * 256 + threadIdx.x;
    if (e < N_EDGES) atomicAdd(&deg[dst[e]], 1);
}

__global__ __launch_bounds__(256) void k_scan1(const int* __restrict__ deg,
                                               int* __restrict__ incl, int* __restrict__ bsum)
{
    __shared__ int s[256];
    int t = threadIdx.x;
    int i = blockIdx.x * 256 + t;
    s[t] = (i < N_NODES) ? deg[i] : 0;
    __syncthreads();
    for (int off = 1; off < 256; off <<= 1) {
        int x = (t >= off) ? s[t - off] : 0;
        __syncthreads();
        s[t] += x;
        __syncthreads();
    }
    if (i < N_NODES) incl[i] = s[t];
    if (t == 255) bsum[blockIdx.x] = s[255];
}

__global__ __launch_bounds__(256) void k_scan2(int* __restrict__ bsum, int nb)
{
    __shared__ int s[256];
    int t = threadIdx.x;
    s[t] = (t < nb) ? bsum[t] : 0;
    __syncthreads();
    for (int off = 1; off < 256; off <<= 1) {
        int x = (t >= off) ? s[t - off] : 0;
        __syncthreads();
        s[t] += x;
        __syncthreads();
    }
    if (t < nb) bsum[t] = s[t];
}

__global__ __launch_bounds__(256) void k_scan3(const int* __restrict__ deg,
                                               const int* __restrict__ incl,
                                               const int* __restrict__ bsum,
                                               int* __restrict__ row_start)
{
    int i = blockIdx.x * 256 + threadIdx.x;
    if (i < N_NODES) {
        int boff = (blockIdx.x > 0) ? bsum[blockIdx.x - 1] : 0;
        row_start[i] = incl[i] - deg[i] + boff;
    }
}

__global__ __launch_bounds__(256) void k_scatter(const int* __restrict__ src,
                                                 const int* __restrict__ dst,
                                                 const int* __restrict__ row_start,
                                                 int* __restrict__ cur, int* __restrict__ esrc)
{
    int e = blockIdx.x * 256 + threadIdx.x;
    if (e < N_EDGES) {
        int d = dst[e];
        int pos = row_start[d] + atomicAdd(&cur[d], 1);
        esrc[pos] = src[e];
    }
}

// ---------------------------------------------------------------------------
// Softmax + aggregation in ONE pass, no max subtraction (|e| <= ~10, exp is
// fp32-safe; exp(e)/sum(exp(e)) == exp(e-m)/sum(exp(e-m)) exactly in real
// arithmetic). One wave per dst node. Lane l owns features l and l+64 (both
// head l&7). agg = (sum w*y) / (sum w); deg-0 guard writes 0 (ref: empty
// segment -> 0).
// ---------------------------------------------------------------------------
__global__ __launch_bounds__(64) void k_node_agg(
    const int* __restrict__ esrc, const int* __restrict__ row_start,
    const int* __restrict__ deg,
    const float* __restrict__ su, const float* __restrict__ sv,
    const ushort_t* __restrict__ yb, float* __restrict__ agg)
{
    const int n = blockIdx.x, l = threadIdx.x;
    const int start = row_start[n], d = deg[n];
    const int h0 = l & 7;
    const float svh = sv[n*H + h0];

    float ssum = 0.f, acc0 = 0.f, acc1 = 0.f;
    int i = 0;
    for (; i + 2 <= d; i += 2) {
        int s0 = __builtin_amdgcn_readfirstlane(esrc[start + i]);
        int s1 = __builtin_amdgcn_readfirstlane(esrc[start + i + 1]);
        float e0 = su[s0*H + h0] + svh;
        float e1 = su[s1*H + h0] + svh;
        ushort_t ya0 = yb[(size_t)s0*DIM + l];
        ushort_t yb0 = yb[(size_t)s0*DIM + 64 + l];
        ushort_t ya1 = yb[(size_t)s1*DIM + l];
        ushort_t yb1 = yb[(size_t)s1*DIM + 64 + l];
        e0 = (e0 >= 0.f) ? e0 : 0.2f * e0;
        e1 = (e1 >= 0.f) ? e1 : 0.2f * e1;
        float w0 = __expf(e0);
        float w1 = __expf(e1);
        ssum += w0 + w1;
        acc0 += w0 * bf2f(ya0) + w1 * bf2f(ya1);
        acc1 += w0 * bf2f(yb0) + w1 * bf2f(yb1);
    }
    if (i < d) {
        int s0 = __builtin_amdgcn_readfirstlane(esrc[start + i]);
        float e0 = su[s0*H + h0] + svh;
        e0 = (e0 >= 0.f) ? e0 : 0.2f * e0;
        float w0 = __expf(e0);
        ssum += w0;
        acc0 += w0 * bf2f(yb[(size_t)s0*DIM + l]);
        acc1 += w0 * bf2f(yb[(size_t)s0*DIM + 64 + l]);
    }
    float r = (ssum > 0.f) ? (1.0f / ssum) : 0.f;
    agg[(size_t)n*DIM + l]      = acc0 * r;
    agg[(size_t)n*DIM + 64 + l] = acc1 * r;
}

// ---------------------------------------------------------------------------
extern "C" void kernel_launch(void* const* d_in, const int* in_sizes, int n_in,
                              void* d_out, int out_size, void* d_ws, size_t ws_size,
                              hipStream_t stream)
{
    const float* x     = (const float*)d_in[0];
    const int*   src   = (const int*)  d_in[1];
    const int*   dst   = (const int*)  d_in[2];
    const float* gamma = (const float*)d_in[3];
    const float* beta  = (const float*)d_in[4];
    const float* W_in  = (const float*)d_in[5];
    const float* b_in  = (const float*)d_in[6];
    const float* W_u   = (const float*)d_in[7];
    const float* b_u   = (const float*)d_in[8];
    const float* W_v   = (const float*)d_in[9];
    const float* W_ff  = (const float*)d_in[10];
    const float* b_ff  = (const float*)d_in[11];
    float* out = (float*)d_out;

    char* ws = (char*)d_ws;
    ushort_t* yb     = (ushort_t*)ws; ws += (size_t)N_NODES * DIM * 2;
    float* agg       = (float*)ws; ws += (size_t)N_NODES * DIM * 4;
    float* su        = (float*)ws; ws += (size_t)N_NODES * H * 4;
    float* sv        = (float*)ws; ws += (size_t)N_NODES * H * 4;
    int*   deg       = (int*)  ws; ws += (size_t)N_NODES * 4;
    int*   cur       = (int*)  ws; ws += (size_t)N_NODES * 4;
    int*   incl      = (int*)  ws; ws += (size_t)N_NODES * 4;
    int*   row_start = (int*)  ws; ws += (size_t)N_NODES * 4;
    int*   bsum      = (int*)  ws; ws += 1024;
    int*   esrc      = (int*)  ws; ws += (size_t)N_EDGES * 4;

    const int NB_NODE = (N_NODES + 255) / 256;   // 196
    const int NB_EDGE = (N_EDGES + 255) / 256;   // 3125
    const int NB_GEMM = (N_NODES + 63) / 64;     // 782

    hipLaunchKernelGGL(k_zero, dim3(NB_NODE), dim3(256), 0, stream, deg, cur);
    hipLaunchKernelGGL((k_gemm128<true, true>), dim3(NB_GEMM), dim3(256), 0, stream,
                       x, W_in, b_in, gamma, beta, (float*)nullptr, yb);
    hipLaunchKernelGGL(k_scores, dim3(N_NODES / 4), dim3(256), 0, stream,
                       yb, W_u, b_u, W_v, su, sv);
    hipLaunchKernelGGL(k_hist, dim3(NB_EDGE), dim3(256), 0, stream, dst, deg);
    hipLaunchKernelGGL(k_scan1, dim3(NB_NODE), dim3(256), 0, stream, deg, incl, bsum);
    hipLaunchKernelGGL(k_scan2, dim3(1), dim3(256), 0, stream, bsum, NB_NODE);
    hipLaunchKernelGGL(k_scan3, dim3(NB_NODE), dim3(256), 0, stream, deg, incl, bsum, row_start);
    hipLaunchKernelGGL(k_scatter, dim3(NB_EDGE), dim3(256), 0, stream,
                       src, dst, row_start, cur, esrc);
    hipLaunchKernelGGL(k_node_agg, dim3(N_NODES), dim3(64), 0, stream,
                       esrc, row_start, deg, su, sv, yb, agg);
    hipLaunchKernelGGL((k_gemm128<false, false>), dim3(NB_GEMM), dim3(256), 0, stream,
                       agg, W_ff, b_ff, (float*)nullptr, (float*)nullptr, out, (ushort_t*)nullptr);
}

// Round 5
// 264.735 us; speedup vs baseline: 5.0148x; 1.1700x over previous
//
#include <hip/hip_runtime.h>

#define N_NODES 50000
#define N_EDGES 800000
#define DIM 128
#define H 8

typedef unsigned short ushort_t;
typedef unsigned int uint_t;
typedef __attribute__((ext_vector_type(8))) short bf16x8;
typedef __attribute__((ext_vector_type(4))) float f32x4;

__device__ __forceinline__ float bf2f(ushort_t u) {
    return __uint_as_float(((uint_t)u) << 16);
}
__device__ __forceinline__ ushort_t f2bf(float f) {
    uint_t x = __float_as_uint(f);
    uint_t r = (x + 0x7FFFu + ((x >> 16) & 1u)) >> 16;   // RNE
    return (ushort_t)r;
}

// ---------------------------------------------------------------------------
// MFMA GEMM: Y[n][c] = sum_k A[n][k] * W[k][c] + bias[c], A = LN(X) or bf16 Ab.
// Block 256 thr = 4 waves, 64 nodes (wave w -> 16 nodes). K=N=128.
// W^T staged in LDS bf16 with XOR swizzle: element W[k][n] lives at
//   wt[n*128 + (((k>>3) ^ (n&15))<<3) + (k&7)]
// -> B-frag (n=lane&15 fixed, 8 consecutive k) is one conflict-free
//    16B-aligned ds_read_b128.
// A-frag layout (16x16x32): m = lane&15, k = (lane>>4)*8 + j  [m120/m89].
// C/D layout: col = lane&15, row = (lane>>4)*4 + reg          [m89].
// ---------------------------------------------------------------------------
template<bool DO_LN, bool BF16_OUT>
__global__ __launch_bounds__(256) void k_gemm_mfma(
    const float* __restrict__ X, const ushort_t* __restrict__ Ab,
    const float* __restrict__ W, const float* __restrict__ bias,
    const float* __restrict__ gamma, const float* __restrict__ beta,
    float* __restrict__ Yf, ushort_t* __restrict__ Yb)
{
    __shared__ ushort_t wt[128 * 128];   // 32 KB swizzled W^T (bf16)

    const int t  = threadIdx.x;
    const int n0 = blockIdx.x * 64;
    const int l  = t & 63, w = t >> 6;
    const int m  = l & 15, q = l >> 4;

    // ---- Stage W^T (bf16, swizzled). 4096 float4 / 256 thr = 16 reps.
    #pragma unroll 4
    for (int rep = 0; rep < 16; ++rep) {
        int id = rep * 256 + t;          // 0..4095
        int k  = id >> 5;                // 0..127
        int n4 = (id & 31) << 2;         // 0,4,...,124
        float4 wv = *(const float4*)(W + (size_t)k * DIM + n4);
        int kb = k >> 3, kj = k & 7;
        wt[(n4+0)*128 + ((kb ^ ((n4+0) & 15)) << 3) + kj] = f2bf(wv.x);
        wt[(n4+1)*128 + ((kb ^ ((n4+1) & 15)) << 3) + kj] = f2bf(wv.y);
        wt[(n4+2)*128 + ((kb ^ ((n4+2) & 15)) << 3) + kj] = f2bf(wv.z);
        wt[(n4+3)*128 + ((kb ^ ((n4+3) & 15)) << 3) + kj] = f2bf(wv.w);
    }

    // ---- Build A-fragments (before the barrier; LDS not needed for A)
    const int node = n0 + w * 16 + m;
    const int nc   = (node < N_NODES) ? node : (N_NODES - 1);
    bf16x8 afrag[4];

    if (DO_LN) {
        const float* xrow = X + (size_t)nc * DIM;
        float xv[4][8];
        float s = 0.f, ss = 0.f;
        #pragma unroll
        for (int ks = 0; ks < 4; ++ks) {
            int base = 32 * ks + 8 * q;
            float4 a0 = *(const float4*)(xrow + base);
            float4 a1 = *(const float4*)(xrow + base + 4);
            xv[ks][0]=a0.x; xv[ks][1]=a0.y; xv[ks][2]=a0.z; xv[ks][3]=a0.w;
            xv[ks][4]=a1.x; xv[ks][5]=a1.y; xv[ks][6]=a1.z; xv[ks][7]=a1.w;
            #pragma unroll
            for (int j = 0; j < 8; ++j) { s += xv[ks][j]; ss += xv[ks][j]*xv[ks][j]; }
        }
        // reduce across the 4 lanes sharing m (xor bits 4,5)
        s  += __shfl_xor(s, 16);  s  += __shfl_xor(s, 32);
        ss += __shfl_xor(ss, 16); ss += __shfl_xor(ss, 32);
        float mu   = s * (1.f / DIM);
        float var  = ss * (1.f / DIM) - mu * mu;
        float rstd = rsqrtf(var + 1e-5f);
        #pragma unroll
        for (int ks = 0; ks < 4; ++ks) {
            int base = 32 * ks + 8 * q;
            float4 g0 = *(const float4*)(gamma + base);
            float4 g1 = *(const float4*)(gamma + base + 4);
            float4 b0 = *(const float4*)(beta + base);
            float4 b1 = *(const float4*)(beta + base + 4);
            float gg[8] = {g0.x,g0.y,g0.z,g0.w,g1.x,g1.y,g1.z,g1.w};
            float bb[8] = {b0.x,b0.y,b0.z,b0.w,b1.x,b1.y,b1.z,b1.w};
            #pragma unroll
            for (int j = 0; j < 8; ++j) {
                float xn = (xv[ks][j] - mu) * rstd * gg[j] + bb[j];
                afrag[ks][j] = (short)f2bf(xn);
            }
        }
    } else {
        const ushort_t* arow = Ab + (size_t)nc * DIM;
        #pragma unroll
        for (int ks = 0; ks < 4; ++ks)
            afrag[ks] = *(const bf16x8*)(arow + 32 * ks + 8 * q);
    }

    __syncthreads();

    // ---- MFMA main: 8 col-tiles x 4 k-steps
    f32x4 acc[8];
    #pragma unroll
    for (int c = 0; c < 8; ++c) acc[c] = (f32x4){0.f, 0.f, 0.f, 0.f};

    #pragma unroll
    for (int ks = 0; ks < 4; ++ks) {
        int k8 = ks * 4 + q;
        #pragma unroll
        for (int c = 0; c < 8; ++c) {
            int n = c * 16 + m;
            bf16x8 bfrag = *(const bf16x8*)(wt + n * 128 + ((k8 ^ m) << 3));
            acc[c] = __builtin_amdgcn_mfma_f32_16x16x32_bf16(afrag[ks], bfrag, acc[c], 0, 0, 0);
        }
    }

    // ---- Epilogue: row = q*4 + r, col = c*16 + m
    #pragma unroll
    for (int c = 0; c < 8; ++c) {
        int col = c * 16 + m;
        float bb = bias[col];
        #pragma unroll
        for (int r = 0; r < 4; ++r) {
            int nn = n0 + w * 16 + q * 4 + r;
            if (nn < N_NODES) {
                float v = acc[c][r] + bb;
                if (BF16_OUT) Yb[(size_t)nn * DIM + col] = f2bf(v);
                else          Yf[(size_t)nn * DIM + col] = v;
            }
        }
    }
}

// ---------------------------------------------------------------------------
// Scores from bf16 y: su = y@W_u + b_u, sv = y@W_v. One wave per node.
// ---------------------------------------------------------------------------
__global__ __launch_bounds__(256) void k_scores(
    const ushort_t* __restrict__ yb, const float* __restrict__ W_u,
    const float* __restrict__ b_u, const float* __restrict__ W_v,
    float* __restrict__ su, float* __restrict__ sv)
{
    __shared__ float ys[4][DIM];
    const int w = threadIdx.x >> 6, l = threadIdx.x & 63;
    const int n = blockIdx.x * 4 + w;   // grid = 12500 -> exact

    ushort2 yy = ((const ushort2*)(yb + (size_t)n * DIM))[l];
    ys[w][l*2]     = bf2f(yy.x);
    ys[w][l*2 + 1] = bf2f(yy.y);
    __syncthreads();

    const int o   = l & 15;   // 0..7: su head, 8..15: sv head
    const int seg = l >> 4;   // k-quarter
    const int h   = o & 7;
    const float* Wm = (o < 8) ? W_u : W_v;
    float sum = 0.f;
    #pragma unroll
    for (int j = 0; j < 32; ++j)
        sum += ys[w][seg*32 + j] * Wm[(seg*32 + j) * H + h];
    sum += __shfl_xor(sum, 16);
    sum += __shfl_xor(sum, 32);
    if (l < 16) {
        if (o < 8) su[n*H + o]       = sum + b_u[o];
        else       sv[n*H + (o - 8)] = sum;
    }
}

// ---------------------------------------------------------------------------
// CSR build: zero, histogram(+rank), 2-level scan, atomic-free scatter
// ---------------------------------------------------------------------------
__global__ __launch_bounds__(256) void k_zero(int* __restrict__ deg)
{
    int i = blockIdx.x * 256 + threadIdx.x;
    if (i < N_NODES) deg[i] = 0;
}

__global__ __launch_bounds__(256) void k_hist(const int* __restrict__ dst,
                                              int* __restrict__ deg, int* __restrict__ rank)
{
    int e = blockIdx.x * 256 + threadIdx.x;
    if (e < N_EDGES) rank[e] = atomicAdd(&deg[dst[e]], 1);
}

__global__ __launch_bounds__(256) void k_scan1(const int* __restrict__ deg,
                                               int* __restrict__ incl, int* __restrict__ bsum)
{
    __shared__ int s[256];
    int t = threadIdx.x;
    int i = blockIdx.x * 256 + t;
    s[t] = (i < N_NODES) ? deg[i] : 0;
    __syncthreads();
    for (int off = 1; off < 256; off <<= 1) {
        int x = (t >= off) ? s[t - off] : 0;
        __syncthreads();
        s[t] += x;
        __syncthreads();
    }
    if (i < N_NODES) incl[i] = s[t];
    if (t == 255) bsum[blockIdx.x] = s[255];
}

__global__ __launch_bounds__(256) void k_scan2(int* __restrict__ bsum, int nb)
{
    __shared__ int s[256];
    int t = threadIdx.x;
    s[t] = (t < nb) ? bsum[t] : 0;
    __syncthreads();
    for (int off = 1; off < 256; off <<= 1) {
        int x = (t >= off) ? s[t - off] : 0;
        __syncthreads();
        s[t] += x;
        __syncthreads();
    }
    if (t < nb) bsum[t] = s[t];
}

__global__ __launch_bounds__(256) void k_scan3(const int* __restrict__ deg,
                                               const int* __restrict__ incl,
                                               const int* __restrict__ bsum,
                                               int* __restrict__ row_start)
{
    int i = blockIdx.x * 256 + threadIdx.x;
    if (i < N_NODES) {
        int boff = (blockIdx.x > 0) ? bsum[blockIdx.x - 1] : 0;
        row_start[i] = incl[i] - deg[i] + boff;
    }
}

__global__ __launch_bounds__(256) void k_scatter(const int* __restrict__ src,
                                                 const int* __restrict__ dst,
                                                 const int* __restrict__ row_start,
                                                 const int* __restrict__ rank,
                                                 int* __restrict__ esrc)
{
    int e = blockIdx.x * 256 + threadIdx.x;
    if (e < N_EDGES) {
        int d = dst[e];
        esrc[row_start[d] + rank[e]] = src[e];
    }
}

// ---------------------------------------------------------------------------
// Softmax + aggregation in one pass (no max subtraction; |e|<=~10 so exp is
// fp32-safe). One wave per dst node; lane l owns features l and l+64 (both
// head l&7). Output bf16. deg-0 -> 0 (ref: empty segment -> 0).
// ---------------------------------------------------------------------------
__global__ __launch_bounds__(64) void k_node_agg(
    const int* __restrict__ esrc, const int* __restrict__ row_start,
    const int* __restrict__ deg,
    const float* __restrict__ su, const float* __restrict__ sv,
    const ushort_t* __restrict__ yb, ushort_t* __restrict__ aggb)
{
    const int n = blockIdx.x, l = threadIdx.x;
    const int start = row_start[n], d = deg[n];
    const int h0 = l & 7;
    const float svh = sv[n*H + h0];

    float ssum = 0.f, acc0 = 0.f, acc1 = 0.f;
    int i = 0;
    for (; i + 2 <= d; i += 2) {
        int s0 = __builtin_amdgcn_readfirstlane(esrc[start + i]);
        int s1 = __builtin_amdgcn_readfirstlane(esrc[start + i + 1]);
        float e0 = su[s0*H + h0] + svh;
        float e1 = su[s1*H + h0] + svh;
        ushort_t ya0 = yb[(size_t)s0*DIM + l];
        ushort_t yb0 = yb[(size_t)s0*DIM + 64 + l];
        ushort_t ya1 = yb[(size_t)s1*DIM + l];
        ushort_t yb1 = yb[(size_t)s1*DIM + 64 + l];
        e0 = (e0 >= 0.f) ? e0 : 0.2f * e0;
        e1 = (e1 >= 0.f) ? e1 : 0.2f * e1;
        float w0 = __expf(e0);
        float w1 = __expf(e1);
        ssum += w0 + w1;
        acc0 += w0 * bf2f(ya0) + w1 * bf2f(ya1);
        acc1 += w0 * bf2f(yb0) + w1 * bf2f(yb1);
    }
    if (i < d) {
        int s0 = __builtin_amdgcn_readfirstlane(esrc[start + i]);
        float e0 = su[s0*H + h0] + svh;
        e0 = (e0 >= 0.f) ? e0 : 0.2f * e0;
        float w0 = __expf(e0);
        ssum += w0;
        acc0 += w0 * bf2f(yb[(size_t)s0*DIM + l]);
        acc1 += w0 * bf2f(yb[(size_t)s0*DIM + 64 + l]);
    }
    float r = (ssum > 0.f) ? (1.0f / ssum) : 0.f;
    aggb[(size_t)n*DIM + l]      = f2bf(acc0 * r);
    aggb[(size_t)n*DIM + 64 + l] = f2bf(acc1 * r);
}

// ---------------------------------------------------------------------------
extern "C" void kernel_launch(void* const* d_in, const int* in_sizes, int n_in,
                              void* d_out, int out_size, void* d_ws, size_t ws_size,
                              hipStream_t stream)
{
    const float* x     = (const float*)d_in[0];
    const int*   src   = (const int*)  d_in[1];
    const int*   dst   = (const int*)  d_in[2];
    const float* gamma = (const float*)d_in[3];
    const float* beta  = (const float*)d_in[4];
    const float* W_in  = (const float*)d_in[5];
    const float* b_in  = (const float*)d_in[6];
    const float* W_u   = (const float*)d_in[7];
    const float* b_u   = (const float*)d_in[8];
    const float* W_v   = (const float*)d_in[9];
    const float* W_ff  = (const float*)d_in[10];
    const float* b_ff  = (const float*)d_in[11];
    float* out = (float*)d_out;

    char* ws = (char*)d_ws;
    ushort_t* yb     = (ushort_t*)ws; ws += (size_t)N_NODES * DIM * 2;
    ushort_t* aggb   = (ushort_t*)ws; ws += (size_t)N_NODES * DIM * 2;
    float* su        = (float*)ws; ws += (size_t)N_NODES * H * 4;
    float* sv        = (float*)ws; ws += (size_t)N_NODES * H * 4;
    int*   deg       = (int*)  ws; ws += (size_t)N_NODES * 4;
    int*   incl      = (int*)  ws; ws += (size_t)N_NODES * 4;
    int*   row_start = (int*)  ws; ws += (size_t)N_NODES * 4;
    int*   bsum      = (int*)  ws; ws += 1024;
    int*   rank      = (int*)  ws; ws += (size_t)N_EDGES * 4;
    int*   esrc      = (int*)  ws; ws += (size_t)N_EDGES * 4;

    const int NB_NODE = (N_NODES + 255) / 256;   // 196
    const int NB_EDGE = (N_EDGES + 255) / 256;   // 3125
    const int NB_GEMM = (N_NODES + 63) / 64;     // 782

    hipLaunchKernelGGL(k_zero, dim3(NB_NODE), dim3(256), 0, stream, deg);
    hipLaunchKernelGGL((k_gemm_mfma<true, true>), dim3(NB_GEMM), dim3(256), 0, stream,
                       x, (const ushort_t*)nullptr, W_in, b_in, gamma, beta,
                       (float*)nullptr, yb);
    hipLaunchKernelGGL(k_scores, dim3(N_NODES / 4), dim3(256), 0, stream,
                       yb, W_u, b_u, W_v, su, sv);
    hipLaunchKernelGGL(k_hist, dim3(NB_EDGE), dim3(256), 0, stream, dst, deg, rank);
    hipLaunchKernelGGL(k_scan1, dim3(NB_NODE), dim3(256), 0, stream, deg, incl, bsum);
    hipLaunchKernelGGL(k_scan2, dim3(1), dim3(256), 0, stream, bsum, NB_NODE);
    hipLaunchKernelGGL(k_scan3, dim3(NB_NODE), dim3(256), 0, stream, deg, incl, bsum, row_start);
    hipLaunchKernelGGL(k_scatter, dim3(NB_EDGE), dim3(256), 0, stream,
                       src, dst, row_start, rank, esrc);
    hipLaunchKernelGGL(k_node_agg, dim3(N_NODES), dim3(64), 0, stream,
                       esrc, row_start, deg, su, sv, yb, aggb);
    hipLaunchKernelGGL((k_gemm_mfma<false, false>), dim3(NB_GEMM), dim3(256), 0, stream,
                       (const float*)nullptr, aggb, W_ff, b_ff,
                       (const float*)nullptr, (const float*)nullptr,
                       out, (ushort_t*)nullptr);
}

// Round 6
// 243.807 us; speedup vs baseline: 5.4452x; 1.0858x over previous
//
#include <hip/hip_runtime.h>

#define N_NODES 50000
#define N_EDGES 800000
#define DIM 128
#define H 8
#define PAD 64   // max stored in-degree; deg~Poisson(16), P(>64)~1e-21. Guarded.

typedef unsigned short ushort_t;
typedef unsigned int uint_t;
typedef __attribute__((ext_vector_type(8))) short bf16x8;
typedef __attribute__((ext_vector_type(4))) float f32x4;

__device__ __forceinline__ float bf2f(ushort_t u) {
    return __uint_as_float(((uint_t)u) << 16);
}
__device__ __forceinline__ ushort_t f2bf(float f) {
    uint_t x = __float_as_uint(f);
    uint_t r = (x + 0x7FFFu + ((x >> 16) & 1u)) >> 16;   // RNE
    return (ushort_t)r;
}

// ---------------------------------------------------------------------------
// MFMA GEMM: Y[n][c] = sum_k A[n][k]*W[k][c] + bias[c]; A = LN(X) or bf16 Ab.
// Block 256 = 4 waves, 64 nodes (wave w -> nodes w*16..w*16+15). K=N=128.
// W^T staged in LDS bf16, XOR-swizzled: W[k][n] at
//   wt[n*128 + (((k>>3) ^ (n&15))<<3) + (k&7)]   -> conflict-free b128 B-frags.
// A-frag (16x16x32): m=lane&15, k=(lane>>4)*8+j. C/D: col=lane&15, row=q*4+reg.
// DO_SCORES: fused su = y@W_u+b_u, sv = y@W_v from the epilogue registers
// (per-lane partials over its 8 cols, xor-butterfly over the m bits).
// ---------------------------------------------------------------------------
template<bool DO_LN, bool BF16_OUT, bool DO_SCORES>
__global__ __launch_bounds__(256) void k_gemm_mfma(
    const float* __restrict__ X, const ushort_t* __restrict__ Ab,
    const float* __restrict__ W, const float* __restrict__ bias,
    const float* __restrict__ gamma, const float* __restrict__ beta,
    const float* __restrict__ W_u, const float* __restrict__ b_u,
    const float* __restrict__ W_v,
    float* __restrict__ Yf, ushort_t* __restrict__ Yb,
    float* __restrict__ su, float* __restrict__ sv)
{
    __shared__ ushort_t wt[128 * 128];     // 32 KB swizzled W^T (bf16)
    __shared__ float    wuvT[2][8 * 128];  // 8 KB: [0]=W_u^T [h][col], [1]=W_v^T

    const int t  = threadIdx.x;
    const int n0 = blockIdx.x * 64;
    const int l  = t & 63, w = t >> 6;
    const int m  = l & 15, q = l >> 4;

    // ---- Stage W^T (bf16, swizzled). 4096 float4 / 256 thr = 16 reps.
    #pragma unroll 4
    for (int rep = 0; rep < 16; ++rep) {
        int id = rep * 256 + t;          // 0..4095
        int k  = id >> 5;                // 0..127
        int n4 = (id & 31) << 2;         // 0,4,...,124
        float4 wv = *(const float4*)(W + (size_t)k * DIM + n4);
        int kb = k >> 3, kj = k & 7;
        wt[(n4+0)*128 + ((kb ^ ((n4+0) & 15)) << 3) + kj] = f2bf(wv.x);
        wt[(n4+1)*128 + ((kb ^ ((n4+1) & 15)) << 3) + kj] = f2bf(wv.y);
        wt[(n4+2)*128 + ((kb ^ ((n4+2) & 15)) << 3) + kj] = f2bf(wv.z);
        wt[(n4+3)*128 + ((kb ^ ((n4+3) & 15)) << 3) + kj] = f2bf(wv.w);
    }
    if (DO_SCORES) {
        #pragma unroll
        for (int i = 0; i < 8; ++i) {
            int g = i * 256 + t;          // 0..2047
            int sel = g >> 10;            // 0: W_u, 1: W_v
            int rem = g & 1023;
            int col = rem >> 3, h = rem & 7;
            float v = sel ? W_v[rem] : W_u[rem];   // [col*8+h], coalesced
            wuvT[sel][h * 128 + col] = v;
        }
    }

    // ---- Build A-fragments (no LDS dependency)
    const int node = n0 + w * 16 + m;
    const int nc   = (node < N_NODES) ? node : (N_NODES - 1);
    bf16x8 afrag[4];

    if (DO_LN) {
        const float* xrow = X + (size_t)nc * DIM;
        float xv[4][8];
        float s = 0.f, ss = 0.f;
        #pragma unroll
        for (int ks = 0; ks < 4; ++ks) {
            int base = 32 * ks + 8 * q;
            float4 a0 = *(const float4*)(xrow + base);
            float4 a1 = *(const float4*)(xrow + base + 4);
            xv[ks][0]=a0.x; xv[ks][1]=a0.y; xv[ks][2]=a0.z; xv[ks][3]=a0.w;
            xv[ks][4]=a1.x; xv[ks][5]=a1.y; xv[ks][6]=a1.z; xv[ks][7]=a1.w;
            #pragma unroll
            for (int j = 0; j < 8; ++j) { s += xv[ks][j]; ss += xv[ks][j]*xv[ks][j]; }
        }
        s  += __shfl_xor(s, 16);  s  += __shfl_xor(s, 32);
        ss += __shfl_xor(ss, 16); ss += __shfl_xor(ss, 32);
        float mu   = s * (1.f / DIM);
        float var  = ss * (1.f / DIM) - mu * mu;
        float rstd = rsqrtf(var + 1e-5f);
        #pragma unroll
        for (int ks = 0; ks < 4; ++ks) {
            int base = 32 * ks + 8 * q;
            float4 g0 = *(const float4*)(gamma + base);
            float4 g1 = *(const float4*)(gamma + base + 4);
            float4 b0 = *(const float4*)(beta + base);
            float4 b1 = *(const float4*)(beta + base + 4);
            float gg[8] = {g0.x,g0.y,g0.z,g0.w,g1.x,g1.y,g1.z,g1.w};
            float bb[8] = {b0.x,b0.y,b0.z,b0.w,b1.x,b1.y,b1.z,b1.w};
            #pragma unroll
            for (int j = 0; j < 8; ++j) {
                float xn = (xv[ks][j] - mu) * rstd * gg[j] + bb[j];
                afrag[ks][j] = (short)f2bf(xn);
            }
        }
    } else {
        const ushort_t* arow = Ab + (size_t)nc * DIM;
        #pragma unroll
        for (int ks = 0; ks < 4; ++ks)
            afrag[ks] = *(const bf16x8*)(arow + 32 * ks + 8 * q);
    }

    __syncthreads();

    // ---- MFMA main: 8 col-tiles x 4 k-steps
    f32x4 acc[8];
    #pragma unroll
    for (int c = 0; c < 8; ++c) acc[c] = (f32x4){0.f, 0.f, 0.f, 0.f};

    #pragma unroll
    for (int ks = 0; ks < 4; ++ks) {
        int k8 = ks * 4 + q;
        #pragma unroll
        for (int c = 0; c < 8; ++c) {
            int n = c * 16 + m;
            bf16x8 bfrag = *(const bf16x8*)(wt + n * 128 + ((k8 ^ m) << 3));
            acc[c] = __builtin_amdgcn_mfma_f32_16x16x32_bf16(afrag[ks], bfrag, acc[c], 0, 0, 0);
        }
    }

    // ---- Epilogue: per r, node nn = n0 + w*16 + q*4 + r; col = c*16 + m
    float bcol[8];
    #pragma unroll
    for (int c = 0; c < 8; ++c) bcol[c] = bias[c * 16 + m];

    #pragma unroll
    for (int r = 0; r < 4; ++r) {
        int nn = n0 + w * 16 + q * 4 + r;
        bool ok = (nn < N_NODES);
        float v[8];
        #pragma unroll
        for (int c = 0; c < 8; ++c) v[c] = acc[c][r] + bcol[c];

        if (ok) {
            #pragma unroll
            for (int c = 0; c < 8; ++c) {
                int col = c * 16 + m;
                if (BF16_OUT) Yb[(size_t)nn * DIM + col] = f2bf(v[c]);
                else          Yf[(size_t)nn * DIM + col] = v[c];
            }
        }

        if (DO_SCORES) {
            float ps[16];
            #pragma unroll
            for (int h = 0; h < 8; ++h) {
                float a = 0.f, b = 0.f;
                #pragma unroll
                for (int c = 0; c < 8; ++c) {
                    int col = c * 16 + m;
                    a += v[c] * wuvT[0][h * 128 + col];
                    b += v[c] * wuvT[1][h * 128 + col];
                }
                ps[h] = a; ps[8 + h] = b;
            }
            #pragma unroll
            for (int o = 1; o < 16; o <<= 1) {
                #pragma unroll
                for (int j = 0; j < 16; ++j) ps[j] += __shfl_xor(ps[j], o);
            }
            if (ok) {
                if (m < 8) su[nn * H + m] = ps[m] + b_u[m];
                else       sv[nn * H + (m - 8)] = ps[m];
            }
        }
    }
}

// ---------------------------------------------------------------------------
// deg = 0
// ---------------------------------------------------------------------------
__global__ __launch_bounds__(256) void k_zero(int* __restrict__ deg)
{
    int i = blockIdx.x * 256 + threadIdx.x;
    if (i < N_NODES) deg[i] = 0;
}

// ---------------------------------------------------------------------------
// Padded-bucket CSR build in ONE kernel (replaces hist+scan x3+scatter):
// esrc_p[d*PAD + pos] = src, pos = atomicAdd(&deg[d],1). pos>=PAD dropped
// (cannot happen for this degree distribution; reader clamps identically).
// ---------------------------------------------------------------------------
__global__ __launch_bounds__(256) void k_build(
    const int* __restrict__ src, const int* __restrict__ dst,
    int* __restrict__ deg, int* __restrict__ esrc_p)
{
    int e = blockIdx.x * 256 + threadIdx.x;
    if (e < N_EDGES) {
        int d = dst[e];
        int pos = atomicAdd(&deg[d], 1);
        if (pos < PAD) esrc_p[d * PAD + pos] = src[e];
    }
}

// ---------------------------------------------------------------------------
// Softmax + aggregation, one pass (no max subtraction: |e|<=~10, exp fp32-
// safe; exp(e)/sum == exp(e-m)/sum(e-m)). One wave per dst node. Lane l owns
// features 2l, 2l+1 (heads 2(l&3), 2(l&3)+1) -> ONE ushort2 gather per edge.
// esrc bucket loaded coalesced once, broadcast via __shfl. deg-0 -> 0.
// ---------------------------------------------------------------------------
__global__ __launch_bounds__(64) void k_node_agg(
    const int* __restrict__ esrc_p, const int* __restrict__ deg,
    const float* __restrict__ su, const float* __restrict__ sv,
    const ushort_t* __restrict__ yb, ushort_t* __restrict__ aggb)
{
    const int n = blockIdx.x, l = threadIdx.x;
    const int d = min(deg[n], PAD);
    const int hp = 2 * (l & 3);                       // head pair base
    const float2 svp = *(const float2*)(sv + n * H + hp);
    const int sl = (l < d) ? esrc_p[n * PAD + l] : 0; // coalesced bucket load

    float ssum0 = 0.f, ssum1 = 0.f, acc0 = 0.f, acc1 = 0.f;
    int i = 0;
    for (; i + 2 <= d; i += 2) {
        int s0 = __shfl(sl, i);
        int s1 = __shfl(sl, i + 1);
        float2 sup0 = *(const float2*)(su + s0 * H + hp);
        float2 sup1 = *(const float2*)(su + s1 * H + hp);
        uint_t yy0 = *(const uint_t*)(yb + (size_t)s0 * DIM + 2 * l);
        uint_t yy1 = *(const uint_t*)(yb + (size_t)s1 * DIM + 2 * l);
        float e00 = sup0.x + svp.x; e00 = (e00 >= 0.f) ? e00 : 0.2f * e00;
        float e01 = sup0.y + svp.y; e01 = (e01 >= 0.f) ? e01 : 0.2f * e01;
        float e10 = sup1.x + svp.x; e10 = (e10 >= 0.f) ? e10 : 0.2f * e10;
        float e11 = sup1.y + svp.y; e11 = (e11 >= 0.f) ? e11 : 0.2f * e11;
        float w00 = __expf(e00), w01 = __expf(e01);
        float w10 = __expf(e10), w11 = __expf(e11);
        ssum0 += w00 + w10; ssum1 += w01 + w11;
        acc0 += w00 * bf2f((ushort_t)(yy0 & 0xFFFF)) + w10 * bf2f((ushort_t)(yy1 & 0xFFFF));
        acc1 += w01 * bf2f((ushort_t)(yy0 >> 16))    + w11 * bf2f((ushort_t)(yy1 >> 16));
    }
    if (i < d) {
        int s0 = __shfl(sl, i);
        float2 sup0 = *(const float2*)(su + s0 * H + hp);
        uint_t yy0 = *(const uint_t*)(yb + (size_t)s0 * DIM + 2 * l);
        float e00 = sup0.x + svp.x; e00 = (e00 >= 0.f) ? e00 : 0.2f * e00;
        float e01 = sup0.y + svp.y; e01 = (e01 >= 0.f) ? e01 : 0.2f * e01;
        float w00 = __expf(e00), w01 = __expf(e01);
        ssum0 += w00; ssum1 += w01;
        acc0 += w00 * bf2f((ushort_t)(yy0 & 0xFFFF));
        acc1 += w01 * bf2f((ushort_t)(yy0 >> 16));
    }
    float r0 = (ssum0 > 0.f) ? (1.0f / ssum0) : 0.f;
    float r1 = (ssum1 > 0.f) ? (1.0f / ssum1) : 0.f;
    uint_t o = (uint_t)f2bf(acc0 * r0) | ((uint_t)f2bf(acc1 * r1) << 16);
    *(uint_t*)(aggb + (size_t)n * DIM + 2 * l) = o;
}

// ---------------------------------------------------------------------------
extern "C" void kernel_launch(void* const* d_in, const int* in_sizes, int n_in,
                              void* d_out, int out_size, void* d_ws, size_t ws_size,
                              hipStream_t stream)
{
    const float* x     = (const float*)d_in[0];
    const int*   src   = (const int*)  d_in[1];
    const int*   dst   = (const int*)  d_in[2];
    const float* gamma = (const float*)d_in[3];
    const float* beta  = (const float*)d_in[4];
    const float* W_in  = (const float*)d_in[5];
    const float* b_in  = (const float*)d_in[6];
    const float* W_u   = (const float*)d_in[7];
    const float* b_u   = (const float*)d_in[8];
    const float* W_v   = (const float*)d_in[9];
    const float* W_ff  = (const float*)d_in[10];
    const float* b_ff  = (const float*)d_in[11];
    float* out = (float*)d_out;

    char* ws = (char*)d_ws;
    ushort_t* yb     = (ushort_t*)ws; ws += (size_t)N_NODES * DIM * 2;
    ushort_t* aggb   = (ushort_t*)ws; ws += (size_t)N_NODES * DIM * 2;
    float* su        = (float*)ws; ws += (size_t)N_NODES * H * 4;
    float* sv        = (float*)ws; ws += (size_t)N_NODES * H * 4;
    int*   deg       = (int*)  ws; ws += (size_t)N_NODES * 4;
    int*   esrc_p    = (int*)  ws; ws += (size_t)N_NODES * PAD * 4;

    const int NB_NODE = (N_NODES + 255) / 256;   // 196
    const int NB_EDGE = (N_EDGES + 255) / 256;   // 3125
    const int NB_GEMM = (N_NODES + 63) / 64;     // 782

    hipLaunchKernelGGL(k_zero, dim3(NB_NODE), dim3(256), 0, stream, deg);
    hipLaunchKernelGGL((k_gemm_mfma<true, true, true>), dim3(NB_GEMM), dim3(256), 0, stream,
                       x, (const ushort_t*)nullptr, W_in, b_in, gamma, beta,
                       W_u, b_u, W_v,
                       (float*)nullptr, yb, su, sv);
    hipLaunchKernelGGL(k_build, dim3(NB_EDGE), dim3(256), 0, stream,
                       src, dst, deg, esrc_p);
    hipLaunchKernelGGL(k_node_agg, dim3(N_NODES), dim3(64), 0, stream,
                       esrc_p, deg, su, sv, yb, aggb);
    hipLaunchKernelGGL((k_gemm_mfma<false, false, false>), dim3(NB_GEMM), dim3(256), 0, stream,
                       (const float*)nullptr, aggb, W_ff, b_ff,
                       (const float*)nullptr, (const float*)nullptr,
                       (const float*)nullptr, (const float*)nullptr, (const float*)nullptr,
                       out, (ushort_t*)nullptr, (float*)nullptr, (float*)nullptr);
}

// Round 7
// 238.215 us; speedup vs baseline: 5.5731x; 1.0235x over previous
//
#include <hip/hip_runtime.h>

#define N_NODES 50000
#define N_EDGES 800000
#define DIM 128
#define H 8
#define PAD 64   // max stored in-degree; deg~Poisson(16), P(>64)~1e-21. Guarded.

typedef unsigned short ushort_t;
typedef unsigned int uint_t;
typedef __attribute__((ext_vector_type(8))) short bf16x8;
typedef __attribute__((ext_vector_type(4))) float f32x4;

__device__ __forceinline__ float bf2f(ushort_t u) {
    return __uint_as_float(((uint_t)u) << 16);
}
__device__ __forceinline__ ushort_t f2bf(float f) {
    uint_t x = __float_as_uint(f);
    uint_t r = (x + 0x7FFFu + ((x >> 16) & 1u)) >> 16;   // RNE
    return (ushort_t)r;
}

// ---------------------------------------------------------------------------
// MFMA GEMM: Y[n][c] = sum_k A[n][k]*W[k][c] + bias[c]; A = LN(X) or bf16 Ab.
// Block 256 = 4 waves, 64 nodes (wave w -> nodes w*16..w*16+15). K=N=128.
// W^T staged in LDS bf16, XOR-swizzled: W[k][n] at
//   wt[n*128 + (((k>>3) ^ (n&15))<<3) + (k&7)]   -> conflict-free b128 B-frags.
// A-frag (16x16x32): m=lane&15, k=(lane>>4)*8+j. C/D: col=lane&15, row=q*4+reg.
// DO_SCORES: fused su = y@W_u+b_u, sv = y@W_v from the epilogue registers
// (per-lane partials over its 8 cols, xor-butterfly over the m bits).
// ---------------------------------------------------------------------------
template<bool DO_LN, bool BF16_OUT, bool DO_SCORES>
__global__ __launch_bounds__(256) void k_gemm_mfma(
    const float* __restrict__ X, const ushort_t* __restrict__ Ab,
    const float* __restrict__ W, const float* __restrict__ bias,
    const float* __restrict__ gamma, const float* __restrict__ beta,
    const float* __restrict__ W_u, const float* __restrict__ b_u,
    const float* __restrict__ W_v,
    float* __restrict__ Yf, ushort_t* __restrict__ Yb,
    float* __restrict__ su, float* __restrict__ sv)
{
    __shared__ ushort_t wt[128 * 128];     // 32 KB swizzled W^T (bf16)
    __shared__ float    wuvT[2][8 * 128];  // 8 KB: [0]=W_u^T [h][col], [1]=W_v^T

    const int t  = threadIdx.x;
    const int n0 = blockIdx.x * 64;
    const int l  = t & 63, w = t >> 6;
    const int m  = l & 15, q = l >> 4;

    // ---- Stage W^T (bf16, swizzled). 4096 float4 / 256 thr = 16 reps.
    #pragma unroll 4
    for (int rep = 0; rep < 16; ++rep) {
        int id = rep * 256 + t;          // 0..4095
        int k  = id >> 5;                // 0..127
        int n4 = (id & 31) << 2;         // 0,4,...,124
        float4 wv = *(const float4*)(W + (size_t)k * DIM + n4);
        int kb = k >> 3, kj = k & 7;
        wt[(n4+0)*128 + ((kb ^ ((n4+0) & 15)) << 3) + kj] = f2bf(wv.x);
        wt[(n4+1)*128 + ((kb ^ ((n4+1) & 15)) << 3) + kj] = f2bf(wv.y);
        wt[(n4+2)*128 + ((kb ^ ((n4+2) & 15)) << 3) + kj] = f2bf(wv.z);
        wt[(n4+3)*128 + ((kb ^ ((n4+3) & 15)) << 3) + kj] = f2bf(wv.w);
    }
    if (DO_SCORES) {
        #pragma unroll
        for (int i = 0; i < 8; ++i) {
            int g = i * 256 + t;          // 0..2047
            int sel = g >> 10;            // 0: W_u, 1: W_v
            int rem = g & 1023;
            int col = rem >> 3, h = rem & 7;
            float v = sel ? W_v[rem] : W_u[rem];   // [col*8+h], coalesced
            wuvT[sel][h * 128 + col] = v;
        }
    }

    // ---- Build A-fragments (no LDS dependency)
    const int node = n0 + w * 16 + m;
    const int nc   = (node < N_NODES) ? node : (N_NODES - 1);
    bf16x8 afrag[4];

    if (DO_LN) {
        const float* xrow = X + (size_t)nc * DIM;
        float xv[4][8];
        float s = 0.f, ss = 0.f;
        #pragma unroll
        for (int ks = 0; ks < 4; ++ks) {
            int base = 32 * ks + 8 * q;
            float4 a0 = *(const float4*)(xrow + base);
            float4 a1 = *(const float4*)(xrow + base + 4);
            xv[ks][0]=a0.x; xv[ks][1]=a0.y; xv[ks][2]=a0.z; xv[ks][3]=a0.w;
            xv[ks][4]=a1.x; xv[ks][5]=a1.y; xv[ks][6]=a1.z; xv[ks][7]=a1.w;
            #pragma unroll
            for (int j = 0; j < 8; ++j) { s += xv[ks][j]; ss += xv[ks][j]*xv[ks][j]; }
        }
        s  += __shfl_xor(s, 16);  s  += __shfl_xor(s, 32);
        ss += __shfl_xor(ss, 16); ss += __shfl_xor(ss, 32);
        float mu   = s * (1.f / DIM);
        float var  = ss * (1.f / DIM) - mu * mu;
        float rstd = rsqrtf(var + 1e-5f);
        #pragma unroll
        for (int ks = 0; ks < 4; ++ks) {
            int base = 32 * ks + 8 * q;
            float4 g0 = *(const float4*)(gamma + base);
            float4 g1 = *(const float4*)(gamma + base + 4);
            float4 b0 = *(const float4*)(beta + base);
            float4 b1 = *(const float4*)(beta + base + 4);
            float gg[8] = {g0.x,g0.y,g0.z,g0.w,g1.x,g1.y,g1.z,g1.w};
            float bb[8] = {b0.x,b0.y,b0.z,b0.w,b1.x,b1.y,b1.z,b1.w};
            #pragma unroll
            for (int j = 0; j < 8; ++j) {
                float xn = (xv[ks][j] - mu) * rstd * gg[j] + bb[j];
                afrag[ks][j] = (short)f2bf(xn);
            }
        }
    } else {
        const ushort_t* arow = Ab + (size_t)nc * DIM;
        #pragma unroll
        for (int ks = 0; ks < 4; ++ks)
            afrag[ks] = *(const bf16x8*)(arow + 32 * ks + 8 * q);
    }

    __syncthreads();

    // ---- MFMA main: 8 col-tiles x 4 k-steps
    f32x4 acc[8];
    #pragma unroll
    for (int c = 0; c < 8; ++c) acc[c] = (f32x4){0.f, 0.f, 0.f, 0.f};

    #pragma unroll
    for (int ks = 0; ks < 4; ++ks) {
        int k8 = ks * 4 + q;
        #pragma unroll
        for (int c = 0; c < 8; ++c) {
            int n = c * 16 + m;
            bf16x8 bfrag = *(const bf16x8*)(wt + n * 128 + ((k8 ^ m) << 3));
            acc[c] = __builtin_amdgcn_mfma_f32_16x16x32_bf16(afrag[ks], bfrag, acc[c], 0, 0, 0);
        }
    }

    // ---- Epilogue: per r, node nn = n0 + w*16 + q*4 + r; col = c*16 + m
    float bcol[8];
    #pragma unroll
    for (int c = 0; c < 8; ++c) bcol[c] = bias[c * 16 + m];

    #pragma unroll
    for (int r = 0; r < 4; ++r) {
        int nn = n0 + w * 16 + q * 4 + r;
        bool ok = (nn < N_NODES);
        float v[8];
        #pragma unroll
        for (int c = 0; c < 8; ++c) v[c] = acc[c][r] + bcol[c];

        if (ok) {
            #pragma unroll
            for (int c = 0; c < 8; ++c) {
                int col = c * 16 + m;
                if (BF16_OUT) Yb[(size_t)nn * DIM + col] = f2bf(v[c]);
                else          Yf[(size_t)nn * DIM + col] = v[c];
            }
        }

        if (DO_SCORES) {
            float ps[16];
            #pragma unroll
            for (int h = 0; h < 8; ++h) {
                float a = 0.f, b = 0.f;
                #pragma unroll
                for (int c = 0; c < 8; ++c) {
                    int col = c * 16 + m;
                    a += v[c] * wuvT[0][h * 128 + col];
                    b += v[c] * wuvT[1][h * 128 + col];
                }
                ps[h] = a; ps[8 + h] = b;
            }
            #pragma unroll
            for (int o = 1; o < 16; o <<= 1) {
                #pragma unroll
                for (int j = 0; j < 16; ++j) ps[j] += __shfl_xor(ps[j], o);
            }
            if (ok) {
                if (m < 8) su[nn * H + m] = ps[m] + b_u[m];
                else       sv[nn * H + (m - 8)] = ps[m];
            }
        }
    }
}

// ---------------------------------------------------------------------------
// deg = 0
// ---------------------------------------------------------------------------
__global__ __launch_bounds__(256) void k_zero(int* __restrict__ deg)
{
    int i = blockIdx.x * 256 + threadIdx.x;
    if (i < N_NODES) deg[i] = 0;
}

// ---------------------------------------------------------------------------
// Padded-bucket CSR build, ushort payload (src < 50000 < 65536).
// Bucket row = 64 x u16 = 128 B -> per-XCD dirty set ~6.4 MB, line-coalesces
// in L2 far better than the 12.8 MB int version.
// ---------------------------------------------------------------------------
__global__ __launch_bounds__(256) void k_build(
    const int* __restrict__ src, const int* __restrict__ dst,
    int* __restrict__ deg, ushort_t* __restrict__ esrc_p)
{
    int e = blockIdx.x * 256 + threadIdx.x;
    if (e < N_EDGES) {
        int d = dst[e];
        int pos = atomicAdd(&deg[d], 1);
        if (pos < PAD) esrc_p[(size_t)d * PAD + pos] = (ushort_t)src[e];
    }
}

// ---------------------------------------------------------------------------
// Softmax + aggregation, one pass (no max subtraction: |e|<=~10, exp fp32-
// safe). Block = 128 thr = 2 waves = 2 dst nodes (2x resident waves/CU vs
// 64-thr blocks). Lane l owns features 2l, 2l+1 (heads 2(l&3), 2(l&3)+1) ->
// ONE dword y-gather per edge per lane. Bucket row (128 B) loaded coalesced
// once, broadcast via __shfl. 4-edge unroll -> 8 loads in flight. deg-0 -> 0.
// ---------------------------------------------------------------------------
__global__ __launch_bounds__(128) void k_node_agg(
    const ushort_t* __restrict__ esrc_p, const int* __restrict__ deg,
    const float* __restrict__ su, const float* __restrict__ sv,
    const ushort_t* __restrict__ yb, ushort_t* __restrict__ aggb)
{
    const int w = threadIdx.x >> 6, l = threadIdx.x & 63;
    const int n = blockIdx.x * 2 + w;
    const int d = min(deg[n], PAD);
    const int hp = 2 * (l & 3);                       // head pair base
    const float2 svp = *(const float2*)(sv + n * H + hp);
    const int sl = (l < d) ? (int)esrc_p[(size_t)n * PAD + l] : 0;

    float ssum0 = 0.f, ssum1 = 0.f, acc0 = 0.f, acc1 = 0.f;
    int i = 0;
    for (; i + 4 <= d; i += 4) {
        int s0 = __shfl(sl, i);
        int s1 = __shfl(sl, i + 1);
        int s2 = __shfl(sl, i + 2);
        int s3 = __shfl(sl, i + 3);
        float2 u0 = *(const float2*)(su + s0 * H + hp);
        float2 u1 = *(const float2*)(su + s1 * H + hp);
        float2 u2 = *(const float2*)(su + s2 * H + hp);
        float2 u3 = *(const float2*)(su + s3 * H + hp);
        uint_t y0 = *(const uint_t*)(yb + (size_t)s0 * DIM + 2 * l);
        uint_t y1 = *(const uint_t*)(yb + (size_t)s1 * DIM + 2 * l);
        uint_t y2 = *(const uint_t*)(yb + (size_t)s2 * DIM + 2 * l);
        uint_t y3 = *(const uint_t*)(yb + (size_t)s3 * DIM + 2 * l);

        float e0x = u0.x + svp.x; e0x = (e0x >= 0.f) ? e0x : 0.2f * e0x;
        float e0y = u0.y + svp.y; e0y = (e0y >= 0.f) ? e0y : 0.2f * e0y;
        float e1x = u1.x + svp.x; e1x = (e1x >= 0.f) ? e1x : 0.2f * e1x;
        float e1y = u1.y + svp.y; e1y = (e1y >= 0.f) ? e1y : 0.2f * e1y;
        float e2x = u2.x + svp.x; e2x = (e2x >= 0.f) ? e2x : 0.2f * e2x;
        float e2y = u2.y + svp.y; e2y = (e2y >= 0.f) ? e2y : 0.2f * e2y;
        float e3x = u3.x + svp.x; e3x = (e3x >= 0.f) ? e3x : 0.2f * e3x;
        float e3y = u3.y + svp.y; e3y = (e3y >= 0.f) ? e3y : 0.2f * e3y;

        float w0x = __expf(e0x), w0y = __expf(e0y);
        float w1x = __expf(e1x), w1y = __expf(e1y);
        float w2x = __expf(e2x), w2y = __expf(e2y);
        float w3x = __expf(e3x), w3y = __expf(e3y);

        ssum0 += (w0x + w1x) + (w2x + w3x);
        ssum1 += (w0y + w1y) + (w2y + w3y);
        acc0 += w0x * bf2f((ushort_t)(y0 & 0xFFFF)) + w1x * bf2f((ushort_t)(y1 & 0xFFFF))
              + w2x * bf2f((ushort_t)(y2 & 0xFFFF)) + w3x * bf2f((ushort_t)(y3 & 0xFFFF));
        acc1 += w0y * bf2f((ushort_t)(y0 >> 16)) + w1y * bf2f((ushort_t)(y1 >> 16))
              + w2y * bf2f((ushort_t)(y2 >> 16)) + w3y * bf2f((ushort_t)(y3 >> 16));
    }
    for (; i < d; ++i) {
        int s0 = __shfl(sl, i);
        float2 u0 = *(const float2*)(su + s0 * H + hp);
        uint_t y0 = *(const uint_t*)(yb + (size_t)s0 * DIM + 2 * l);
        float e0x = u0.x + svp.x; e0x = (e0x >= 0.f) ? e0x : 0.2f * e0x;
        float e0y = u0.y + svp.y; e0y = (e0y >= 0.f) ? e0y : 0.2f * e0y;
        float w0x = __expf(e0x), w0y = __expf(e0y);
        ssum0 += w0x; ssum1 += w0y;
        acc0 += w0x * bf2f((ushort_t)(y0 & 0xFFFF));
        acc1 += w0y * bf2f((ushort_t)(y0 >> 16));
    }
    float r0 = (ssum0 > 0.f) ? (1.0f / ssum0) : 0.f;
    float r1 = (ssum1 > 0.f) ? (1.0f / ssum1) : 0.f;
    uint_t o = (uint_t)f2bf(acc0 * r0) | ((uint_t)f2bf(acc1 * r1) << 16);
    *(uint_t*)(aggb + (size_t)n * DIM + 2 * l) = o;
}

// ---------------------------------------------------------------------------
extern "C" void kernel_launch(void* const* d_in, const int* in_sizes, int n_in,
                              void* d_out, int out_size, void* d_ws, size_t ws_size,
                              hipStream_t stream)
{
    const float* x     = (const float*)d_in[0];
    const int*   src   = (const int*)  d_in[1];
    const int*   dst   = (const int*)  d_in[2];
    const float* gamma = (const float*)d_in[3];
    const float* beta  = (const float*)d_in[4];
    const float* W_in  = (const float*)d_in[5];
    const float* b_in  = (const float*)d_in[6];
    const float* W_u   = (const float*)d_in[7];
    const float* b_u   = (const float*)d_in[8];
    const float* W_v   = (const float*)d_in[9];
    const float* W_ff  = (const float*)d_in[10];
    const float* b_ff  = (const float*)d_in[11];
    float* out = (float*)d_out;

    char* ws = (char*)d_ws;
    ushort_t* yb     = (ushort_t*)ws; ws += (size_t)N_NODES * DIM * 2;
    ushort_t* aggb   = (ushort_t*)ws; ws += (size_t)N_NODES * DIM * 2;
    float* su        = (float*)ws; ws += (size_t)N_NODES * H * 4;
    float* sv        = (float*)ws; ws += (size_t)N_NODES * H * 4;
    int*   deg       = (int*)  ws; ws += (size_t)N_NODES * 4;
    ushort_t* esrc_p = (ushort_t*)ws; ws += (size_t)N_NODES * PAD * 2;

    const int NB_NODE = (N_NODES + 255) / 256;   // 196
    const int NB_EDGE = (N_EDGES + 255) / 256;   // 3125
    const int NB_GEMM = (N_NODES + 63) / 64;     // 782

    hipLaunchKernelGGL(k_zero, dim3(NB_NODE), dim3(256), 0, stream, deg);
    hipLaunchKernelGGL((k_gemm_mfma<true, true, true>), dim3(NB_GEMM), dim3(256), 0, stream,
                       x, (const ushort_t*)nullptr, W_in, b_in, gamma, beta,
                       W_u, b_u, W_v,
                       (float*)nullptr, yb, su, sv);
    hipLaunchKernelGGL(k_build, dim3(NB_EDGE), dim3(256), 0, stream,
                       src, dst, deg, esrc_p);
    hipLaunchKernelGGL(k_node_agg, dim3(N_NODES / 2), dim3(128), 0, stream,
                       esrc_p, deg, su, sv, yb, aggb);
    hipLaunchKernelGGL((k_gemm_mfma<false, false, false>), dim3(NB_GEMM), dim3(256), 0, stream,
                       (const float*)nullptr, aggb, W_ff, b_ff,
                       (const float*)nullptr, (const float*)nullptr,
                       (const float*)nullptr, (const float*)nullptr, (const float*)nullptr,
                       out, (ushort_t*)nullptr, (float*)nullptr, (float*)nullptr);
}

// Round 8
// 215.843 us; speedup vs baseline: 6.1507x; 1.1036x over previous
//
#include <hip/hip_runtime.h>

#define N_NODES 50000
#define N_EDGES 800000
#define DIM 128
#define H 8
#define PAD 64          // max stored in-degree; deg~Poisson(16), P(>64)~1e-21. Guarded.
#define NPART 256       // dst partitions
#define PART_NODES 196  // ceil(50000/256); NPART*PART_NODES = 50176
#define PART_CAP 4096   // entries per partition region (mean 3125, +17 sigma)
#define EPB 2048        // edges per k_part block

typedef unsigned short ushort_t;
typedef unsigned int uint_t;
typedef __attribute__((ext_vector_type(8))) short bf16x8;
typedef __attribute__((ext_vector_type(4))) float f32x4;

__device__ __forceinline__ float bf2f(ushort_t u) {
    return __uint_as_float(((uint_t)u) << 16);
}
__device__ __forceinline__ ushort_t f2bf(float f) {
    uint_t x = __float_as_uint(f);
    uint_t r = (x + 0x7FFFu + ((x >> 16) & 1u)) >> 16;   // RNE
    return (ushort_t)r;
}

// ---------------------------------------------------------------------------
// MFMA GEMM (unchanged from R6): Y = A@W + bias; A = LN(X) fp32 or bf16 Ab.
// DO_SCORES fuses su/sv epilogue.
// ---------------------------------------------------------------------------
template<bool DO_LN, bool BF16_OUT, bool DO_SCORES>
__global__ __launch_bounds__(256) void k_gemm_mfma(
    const float* __restrict__ X, const ushort_t* __restrict__ Ab,
    const float* __restrict__ W, const float* __restrict__ bias,
    const float* __restrict__ gamma, const float* __restrict__ beta,
    const float* __restrict__ W_u, const float* __restrict__ b_u,
    const float* __restrict__ W_v,
    float* __restrict__ Yf, ushort_t* __restrict__ Yb,
    float* __restrict__ su, float* __restrict__ sv)
{
    __shared__ ushort_t wt[128 * 128];     // 32 KB swizzled W^T (bf16)
    __shared__ float    wuvT[2][8 * 128];  // 8 KB: [0]=W_u^T [h][col], [1]=W_v^T

    const int t  = threadIdx.x;
    const int n0 = blockIdx.x * 64;
    const int l  = t & 63, w = t >> 6;
    const int m  = l & 15, q = l >> 4;

    #pragma unroll 4
    for (int rep = 0; rep < 16; ++rep) {
        int id = rep * 256 + t;
        int k  = id >> 5;
        int n4 = (id & 31) << 2;
        float4 wv = *(const float4*)(W + (size_t)k * DIM + n4);
        int kb = k >> 3, kj = k & 7;
        wt[(n4+0)*128 + ((kb ^ ((n4+0) & 15)) << 3) + kj] = f2bf(wv.x);
        wt[(n4+1)*128 + ((kb ^ ((n4+1) & 15)) << 3) + kj] = f2bf(wv.y);
        wt[(n4+2)*128 + ((kb ^ ((n4+2) & 15)) << 3) + kj] = f2bf(wv.z);
        wt[(n4+3)*128 + ((kb ^ ((n4+3) & 15)) << 3) + kj] = f2bf(wv.w);
    }
    if (DO_SCORES) {
        #pragma unroll
        for (int i = 0; i < 8; ++i) {
            int g = i * 256 + t;
            int sel = g >> 10;
            int rem = g & 1023;
            int col = rem >> 3, h = rem & 7;
            float v = sel ? W_v[rem] : W_u[rem];
            wuvT[sel][h * 128 + col] = v;
        }
    }

    const int node = n0 + w * 16 + m;
    const int nc   = (node < N_NODES) ? node : (N_NODES - 1);
    bf16x8 afrag[4];

    if (DO_LN) {
        const float* xrow = X + (size_t)nc * DIM;
        float xv[4][8];
        float s = 0.f, ss = 0.f;
        #pragma unroll
        for (int ks = 0; ks < 4; ++ks) {
            int base = 32 * ks + 8 * q;
            float4 a0 = *(const float4*)(xrow + base);
            float4 a1 = *(const float4*)(xrow + base + 4);
            xv[ks][0]=a0.x; xv[ks][1]=a0.y; xv[ks][2]=a0.z; xv[ks][3]=a0.w;
            xv[ks][4]=a1.x; xv[ks][5]=a1.y; xv[ks][6]=a1.z; xv[ks][7]=a1.w;
            #pragma unroll
            for (int j = 0; j < 8; ++j) { s += xv[ks][j]; ss += xv[ks][j]*xv[ks][j]; }
        }
        s  += __shfl_xor(s, 16);  s  += __shfl_xor(s, 32);
        ss += __shfl_xor(ss, 16); ss += __shfl_xor(ss, 32);
        float mu   = s * (1.f / DIM);
        float var  = ss * (1.f / DIM) - mu * mu;
        float rstd = rsqrtf(var + 1e-5f);
        #pragma unroll
        for (int ks = 0; ks < 4; ++ks) {
            int base = 32 * ks + 8 * q;
            float4 g0 = *(const float4*)(gamma + base);
            float4 g1 = *(const float4*)(gamma + base + 4);
            float4 b0 = *(const float4*)(beta + base);
            float4 b1 = *(const float4*)(beta + base + 4);
            float gg[8] = {g0.x,g0.y,g0.z,g0.w,g1.x,g1.y,g1.z,g1.w};
            float bb[8] = {b0.x,b0.y,b0.z,b0.w,b1.x,b1.y,b1.z,b1.w};
            #pragma unroll
            for (int j = 0; j < 8; ++j) {
                float xn = (xv[ks][j] - mu) * rstd * gg[j] + bb[j];
                afrag[ks][j] = (short)f2bf(xn);
            }
        }
    } else {
        const ushort_t* arow = Ab + (size_t)nc * DIM;
        #pragma unroll
        for (int ks = 0; ks < 4; ++ks)
            afrag[ks] = *(const bf16x8*)(arow + 32 * ks + 8 * q);
    }

    __syncthreads();

    f32x4 acc[8];
    #pragma unroll
    for (int c = 0; c < 8; ++c) acc[c] = (f32x4){0.f, 0.f, 0.f, 0.f};

    #pragma unroll
    for (int ks = 0; ks < 4; ++ks) {
        int k8 = ks * 4 + q;
        #pragma unroll
        for (int c = 0; c < 8; ++c) {
            int n = c * 16 + m;
            bf16x8 bfrag = *(const bf16x8*)(wt + n * 128 + ((k8 ^ m) << 3));
            acc[c] = __builtin_amdgcn_mfma_f32_16x16x32_bf16(afrag[ks], bfrag, acc[c], 0, 0, 0);
        }
    }

    float bcol[8];
    #pragma unroll
    for (int c = 0; c < 8; ++c) bcol[c] = bias[c * 16 + m];

    #pragma unroll
    for (int r = 0; r < 4; ++r) {
        int nn = n0 + w * 16 + q * 4 + r;
        bool ok = (nn < N_NODES);
        float v[8];
        #pragma unroll
        for (int c = 0; c < 8; ++c) v[c] = acc[c][r] + bcol[c];

        if (ok) {
            #pragma unroll
            for (int c = 0; c < 8; ++c) {
                int col = c * 16 + m;
                if (BF16_OUT) Yb[(size_t)nn * DIM + col] = f2bf(v[c]);
                else          Yf[(size_t)nn * DIM + col] = v[c];
            }
        }

        if (DO_SCORES) {
            float ps[16];
            #pragma unroll
            for (int h = 0; h < 8; ++h) {
                float a = 0.f, b = 0.f;
                #pragma unroll
                for (int c = 0; c < 8; ++c) {
                    int col = c * 16 + m;
                    a += v[c] * wuvT[0][h * 128 + col];
                    b += v[c] * wuvT[1][h * 128 + col];
                }
                ps[h] = a; ps[8 + h] = b;
            }
            #pragma unroll
            for (int o = 1; o < 16; o <<= 1) {
                #pragma unroll
                for (int j = 0; j < 16; ++j) ps[j] += __shfl_xor(ps[j], o);
            }
            if (ok) {
                if (m < 8) su[nn * H + m] = ps[m] + b_u[m];
                else       sv[nn * H + (m - 8)] = ps[m];
            }
        }
    }
}

// ---------------------------------------------------------------------------
// Zero the 256 partition counters (1 block).
// ---------------------------------------------------------------------------
__global__ __launch_bounds__(256) void k_zero(int* __restrict__ pcount)
{
    pcount[threadIdx.x] = 0;
}

// ---------------------------------------------------------------------------
// Counting-sort pass 1: partition edges by dst/PART_NODES into NPART regions.
// Per block: LDS histogram -> one global atomicAdd per partition (range
// reservation; ~391 per counter total, uncontended) -> write packed records
// (dst_local<<16 | src) to contiguous per-(block,partition) runs -> L2
// line-coalesced, unlike the old fully-random bucket scatter.
// ---------------------------------------------------------------------------
__global__ __launch_bounds__(256) void k_part(
    const int* __restrict__ src, const int* __restrict__ dst,
    int* __restrict__ pcount, uint_t* __restrict__ pbuf)
{
    __shared__ int hist[NPART];
    __shared__ int base[NPART];
    __shared__ uint_t rec[EPB];
    __shared__ ushort_t rnk[EPB];
    __shared__ unsigned char prt[EPB];

    const int t = threadIdx.x;
    const int e0 = blockIdx.x * EPB;
    hist[t] = 0;
    __syncthreads();

    #pragma unroll
    for (int i = 0; i < EPB / 256; ++i) {
        int idx = i * 256 + t;
        int e = e0 + idx;
        if (e < N_EDGES) {
            int s = src[e], d = dst[e];
            int p = d / PART_NODES;              // 0..255
            int dl = d - p * PART_NODES;         // 0..195
            int r = atomicAdd(&hist[p], 1);      // LDS atomic
            rec[idx] = ((uint_t)dl << 16) | (uint_t)s;
            rnk[idx] = (ushort_t)r;
            prt[idx] = (unsigned char)p;
        }
    }
    __syncthreads();
    base[t] = atomicAdd(&pcount[t], hist[t]);
    __syncthreads();

    #pragma unroll
    for (int i = 0; i < EPB / 256; ++i) {
        int idx = i * 256 + t;
        int e = e0 + idx;
        if (e < N_EDGES) {
            int p = prt[idx];
            int slot = base[p] + (int)rnk[idx];
            if (slot < PART_CAP)
                pbuf[(size_t)p * PART_CAP + slot] = rec[idx];
        }
    }
}

// ---------------------------------------------------------------------------
// Counting-sort pass 2: one block per partition. Scatter the partition's
// records into an LDS bucket array (LDS atomics, free), then dump buckets
// and deg to global fully coalesced. NO global scattered writes.
// ---------------------------------------------------------------------------
__global__ __launch_bounds__(256) void k_bucket(
    const uint_t* __restrict__ pbuf, const int* __restrict__ pcount,
    ushort_t* __restrict__ esrc_p, int* __restrict__ deg)
{
    __shared__ ushort_t buck[PART_NODES * PAD];   // 25088 B
    __shared__ int cnt[PART_NODES];

    const int p = blockIdx.x, t = threadIdx.x;
    for (int i = t; i < PART_NODES; i += 256) cnt[i] = 0;
    __syncthreads();

    const int m = min(pcount[p], PART_CAP);
    for (int i = t; i < m; i += 256) {
        uint_t v = pbuf[(size_t)p * PART_CAP + i];
        int dl = (int)(v >> 16);
        int pos = atomicAdd(&cnt[dl], 1);
        if (pos < PAD) buck[dl * PAD + pos] = (ushort_t)(v & 0xFFFF);
    }
    __syncthreads();

    const int n0 = p * PART_NODES;
    const uint_t* b32 = (const uint_t*)buck;
    uint_t* g32 = (uint_t*)(esrc_p + (size_t)n0 * PAD);
    for (int i = t; i < PART_NODES * PAD / 2; i += 256) g32[i] = b32[i];
    for (int i = t; i < PART_NODES; i += 256) {
        int n = n0 + i;
        if (n < N_NODES) deg[n] = cnt[i];
    }
}

// ---------------------------------------------------------------------------
// Softmax + aggregation (unchanged from R6): one pass, no max subtraction,
// 2 nodes per 128-thr block, lane l owns features 2l,2l+1, 4-edge unroll.
// ---------------------------------------------------------------------------
__global__ __launch_bounds__(128) void k_node_agg(
    const ushort_t* __restrict__ esrc_p, const int* __restrict__ deg,
    const float* __restrict__ su, const float* __restrict__ sv,
    const ushort_t* __restrict__ yb, ushort_t* __restrict__ aggb)
{
    const int w = threadIdx.x >> 6, l = threadIdx.x & 63;
    const int n = blockIdx.x * 2 + w;
    const int d = min(deg[n], PAD);
    const int hp = 2 * (l & 3);
    const float2 svp = *(const float2*)(sv + n * H + hp);
    const int sl = (l < d) ? (int)esrc_p[(size_t)n * PAD + l] : 0;

    float ssum0 = 0.f, ssum1 = 0.f, acc0 = 0.f, acc1 = 0.f;
    int i = 0;
    for (; i + 4 <= d; i += 4) {
        int s0 = __shfl(sl, i);
        int s1 = __shfl(sl, i + 1);
        int s2 = __shfl(sl, i + 2);
        int s3 = __shfl(sl, i + 3);
        float2 u0 = *(const float2*)(su + s0 * H + hp);
        float2 u1 = *(const float2*)(su + s1 * H + hp);
        float2 u2 = *(const float2*)(su + s2 * H + hp);
        float2 u3 = *(const float2*)(su + s3 * H + hp);
        uint_t y0 = *(const uint_t*)(yb + (size_t)s0 * DIM + 2 * l);
        uint_t y1 = *(const uint_t*)(yb + (size_t)s1 * DIM + 2 * l);
        uint_t y2 = *(const uint_t*)(yb + (size_t)s2 * DIM + 2 * l);
        uint_t y3 = *(const uint_t*)(yb + (size_t)s3 * DIM + 2 * l);

        float e0x = u0.x + svp.x; e0x = (e0x >= 0.f) ? e0x : 0.2f * e0x;
        float e0y = u0.y + svp.y; e0y = (e0y >= 0.f) ? e0y : 0.2f * e0y;
        float e1x = u1.x + svp.x; e1x = (e1x >= 0.f) ? e1x : 0.2f * e1x;
        float e1y = u1.y + svp.y; e1y = (e1y >= 0.f) ? e1y : 0.2f * e1y;
        float e2x = u2.x + svp.x; e2x = (e2x >= 0.f) ? e2x : 0.2f * e2x;
        float e2y = u2.y + svp.y; e2y = (e2y >= 0.f) ? e2y : 0.2f * e2y;
        float e3x = u3.x + svp.x; e3x = (e3x >= 0.f) ? e3x : 0.2f * e3x;
        float e3y = u3.y + svp.y; e3y = (e3y >= 0.f) ? e3y : 0.2f * e3y;

        float w0x = __expf(e0x), w0y = __expf(e0y);
        float w1x = __expf(e1x), w1y = __expf(e1y);
        float w2x = __expf(e2x), w2y = __expf(e2y);
        float w3x = __expf(e3x), w3y = __expf(e3y);

        ssum0 += (w0x + w1x) + (w2x + w3x);
        ssum1 += (w0y + w1y) + (w2y + w3y);
        acc0 += w0x * bf2f((ushort_t)(y0 & 0xFFFF)) + w1x * bf2f((ushort_t)(y1 & 0xFFFF))
              + w2x * bf2f((ushort_t)(y2 & 0xFFFF)) + w3x * bf2f((ushort_t)(y3 & 0xFFFF));
        acc1 += w0y * bf2f((ushort_t)(y0 >> 16)) + w1y * bf2f((ushort_t)(y1 >> 16))
              + w2y * bf2f((ushort_t)(y2 >> 16)) + w3y * bf2f((ushort_t)(y3 >> 16));
    }
    for (; i < d; ++i) {
        int s0 = __shfl(sl, i);
        float2 u0 = *(const float2*)(su + s0 * H + hp);
        uint_t y0 = *(const uint_t*)(yb + (size_t)s0 * DIM + 2 * l);
        float e0x = u0.x + svp.x; e0x = (e0x >= 0.f) ? e0x : 0.2f * e0x;
        float e0y = u0.y + svp.y; e0y = (e0y >= 0.f) ? e0y : 0.2f * e0y;
        float w0x = __expf(e0x), w0y = __expf(e0y);
        ssum0 += w0x; ssum1 += w0y;
        acc0 += w0x * bf2f((ushort_t)(y0 & 0xFFFF));
        acc1 += w0y * bf2f((ushort_t)(y0 >> 16));
    }
    float r0 = (ssum0 > 0.f) ? (1.0f / ssum0) : 0.f;
    float r1 = (ssum1 > 0.f) ? (1.0f / ssum1) : 0.f;
    uint_t o = (uint_t)f2bf(acc0 * r0) | ((uint_t)f2bf(acc1 * r1) << 16);
    *(uint_t*)(aggb + (size_t)n * DIM + 2 * l) = o;
}

// ---------------------------------------------------------------------------
extern "C" void kernel_launch(void* const* d_in, const int* in_sizes, int n_in,
                              void* d_out, int out_size, void* d_ws, size_t ws_size,
                              hipStream_t stream)
{
    const float* x     = (const float*)d_in[0];
    const int*   src   = (const int*)  d_in[1];
    const int*   dst   = (const int*)  d_in[2];
    const float* gamma = (const float*)d_in[3];
    const float* beta  = (const float*)d_in[4];
    const float* W_in  = (const float*)d_in[5];
    const float* b_in  = (const float*)d_in[6];
    const float* W_u   = (const float*)d_in[7];
    const float* b_u   = (const float*)d_in[8];
    const float* W_v   = (const float*)d_in[9];
    const float* W_ff  = (const float*)d_in[10];
    const float* b_ff  = (const float*)d_in[11];
    float* out = (float*)d_out;

    char* ws = (char*)d_ws;
    ushort_t* yb     = (ushort_t*)ws; ws += (size_t)N_NODES * DIM * 2;
    ushort_t* aggb   = (ushort_t*)ws; ws += (size_t)N_NODES * DIM * 2;
    float* su        = (float*)ws; ws += (size_t)N_NODES * H * 4;
    float* sv        = (float*)ws; ws += (size_t)N_NODES * H * 4;
    int*   deg       = (int*)  ws; ws += (size_t)N_NODES * 4;
    int*   pcount    = (int*)  ws; ws += (size_t)NPART * 4;
    uint_t* pbuf     = (uint_t*)ws; ws += (size_t)NPART * PART_CAP * 4;
    ushort_t* esrc_p = (ushort_t*)ws; ws += (size_t)NPART * PART_NODES * PAD * 2;

    const int NB_PART = (N_EDGES + EPB - 1) / EPB;   // 391
    const int NB_GEMM = (N_NODES + 63) / 64;         // 782

    hipLaunchKernelGGL(k_zero, dim3(1), dim3(256), 0, stream, pcount);
    hipLaunchKernelGGL((k_gemm_mfma<true, true, true>), dim3(NB_GEMM), dim3(256), 0, stream,
                       x, (const ushort_t*)nullptr, W_in, b_in, gamma, beta,
                       W_u, b_u, W_v,
                       (float*)nullptr, yb, su, sv);
    hipLaunchKernelGGL(k_part, dim3(NB_PART), dim3(256), 0, stream,
                       src, dst, pcount, pbuf);
    hipLaunchKernelGGL(k_bucket, dim3(NPART), dim3(256), 0, stream,
                       pbuf, pcount, esrc_p, deg);
    hipLaunchKernelGGL(k_node_agg, dim3(N_NODES / 2), dim3(128), 0, stream,
                       esrc_p, deg, su, sv, yb, aggb);
    hipLaunchKernelGGL((k_gemm_mfma<false, false, false>), dim3(NB_GEMM), dim3(256), 0, stream,
                       (const float*)nullptr, aggb, W_ff, b_ff,
                       (const float*)nullptr, (const float*)nullptr,
                       (const float*)nullptr, (const float*)nullptr, (const float*)nullptr,
                       out, (ushort_t*)nullptr, (float*)nullptr, (float*)nullptr);
}

// Round 9
// 207.470 us; speedup vs baseline: 6.3989x; 1.0404x over previous
//
#include <hip/hip_runtime.h>

#define N_NODES 50000
#define N_EDGES 800000
#define DIM 128
#define H 8
#define PAD 64          // max stored in-degree; deg~Poisson(16), P(>64)~1e-21. Guarded.
#define NPART 256       // dst partitions
#define PART_NODES 196  // ceil(50000/256); NPART*PART_NODES = 50176
#define PART_CAP 4096   // entries per partition region (mean 3125, +17 sigma)
#define EPB 2048        // edges per k_part block

typedef unsigned short ushort_t;
typedef unsigned int uint_t;
typedef __attribute__((ext_vector_type(8))) short bf16x8;
typedef __attribute__((ext_vector_type(4))) float f32x4;

__device__ __forceinline__ float bf2f(ushort_t u) {
    return __uint_as_float(((uint_t)u) << 16);
}
__device__ __forceinline__ ushort_t f2bf(float f) {
    uint_t x = __float_as_uint(f);
    uint_t r = (x + 0x7FFFu + ((x >> 16) & 1u)) >> 16;   // RNE
    return (ushort_t)r;
}

// ---------------------------------------------------------------------------
// MFMA GEMM: Y = A@W + bias; A = LN(X) fp32 or bf16 Ab. DO_SCORES fuses su/sv
// epilogue and zeroes pcount (block 0) to save a launch.
// ---------------------------------------------------------------------------
template<bool DO_LN, bool BF16_OUT, bool DO_SCORES>
__global__ __launch_bounds__(256) void k_gemm_mfma(
    const float* __restrict__ X, const ushort_t* __restrict__ Ab,
    const float* __restrict__ W, const float* __restrict__ bias,
    const float* __restrict__ gamma, const float* __restrict__ beta,
    const float* __restrict__ W_u, const float* __restrict__ b_u,
    const float* __restrict__ W_v,
    float* __restrict__ Yf, ushort_t* __restrict__ Yb,
    float* __restrict__ su, float* __restrict__ sv,
    int* __restrict__ pcount)
{
    __shared__ ushort_t wt[128 * 128];     // 32 KB swizzled W^T (bf16)
    __shared__ float    wuvT[2][8 * 128];  // 8 KB: [0]=W_u^T [h][col], [1]=W_v^T

    const int t  = threadIdx.x;
    const int n0 = blockIdx.x * 64;
    const int l  = t & 63, w = t >> 6;
    const int m  = l & 15, q = l >> 4;

    if (DO_SCORES && blockIdx.x == 0) pcount[t] = 0;   // t<256 == NPART

    #pragma unroll 4
    for (int rep = 0; rep < 16; ++rep) {
        int id = rep * 256 + t;
        int k  = id >> 5;
        int n4 = (id & 31) << 2;
        float4 wv = *(const float4*)(W + (size_t)k * DIM + n4);
        int kb = k >> 3, kj = k & 7;
        wt[(n4+0)*128 + ((kb ^ ((n4+0) & 15)) << 3) + kj] = f2bf(wv.x);
        wt[(n4+1)*128 + ((kb ^ ((n4+1) & 15)) << 3) + kj] = f2bf(wv.y);
        wt[(n4+2)*128 + ((kb ^ ((n4+2) & 15)) << 3) + kj] = f2bf(wv.z);
        wt[(n4+3)*128 + ((kb ^ ((n4+3) & 15)) << 3) + kj] = f2bf(wv.w);
    }
    if (DO_SCORES) {
        #pragma unroll
        for (int i = 0; i < 8; ++i) {
            int g = i * 256 + t;
            int sel = g >> 10;
            int rem = g & 1023;
            int col = rem >> 3, h = rem & 7;
            float v = sel ? W_v[rem] : W_u[rem];
            wuvT[sel][h * 128 + col] = v;
        }
    }

    const int node = n0 + w * 16 + m;
    const int nc   = (node < N_NODES) ? node : (N_NODES - 1);
    bf16x8 afrag[4];

    if (DO_LN) {
        const float* xrow = X + (size_t)nc * DIM;
        float xv[4][8];
        float s = 0.f, ss = 0.f;
        #pragma unroll
        for (int ks = 0; ks < 4; ++ks) {
            int base = 32 * ks + 8 * q;
            float4 a0 = *(const float4*)(xrow + base);
            float4 a1 = *(const float4*)(xrow + base + 4);
            xv[ks][0]=a0.x; xv[ks][1]=a0.y; xv[ks][2]=a0.z; xv[ks][3]=a0.w;
            xv[ks][4]=a1.x; xv[ks][5]=a1.y; xv[ks][6]=a1.z; xv[ks][7]=a1.w;
            #pragma unroll
            for (int j = 0; j < 8; ++j) { s += xv[ks][j]; ss += xv[ks][j]*xv[ks][j]; }
        }
        s  += __shfl_xor(s, 16);  s  += __shfl_xor(s, 32);
        ss += __shfl_xor(ss, 16); ss += __shfl_xor(ss, 32);
        float mu   = s * (1.f / DIM);
        float var  = ss * (1.f / DIM) - mu * mu;
        float rstd = rsqrtf(var + 1e-5f);
        #pragma unroll
        for (int ks = 0; ks < 4; ++ks) {
            int base = 32 * ks + 8 * q;
            float4 g0 = *(const float4*)(gamma + base);
            float4 g1 = *(const float4*)(gamma + base + 4);
            float4 b0 = *(const float4*)(beta + base);
            float4 b1 = *(const float4*)(beta + base + 4);
            float gg[8] = {g0.x,g0.y,g0.z,g0.w,g1.x,g1.y,g1.z,g1.w};
            float bb[8] = {b0.x,b0.y,b0.z,b0.w,b1.x,b1.y,b1.z,b1.w};
            #pragma unroll
            for (int j = 0; j < 8; ++j) {
                float xn = (xv[ks][j] - mu) * rstd * gg[j] + bb[j];
                afrag[ks][j] = (short)f2bf(xn);
            }
        }
    } else {
        const ushort_t* arow = Ab + (size_t)nc * DIM;
        #pragma unroll
        for (int ks = 0; ks < 4; ++ks)
            afrag[ks] = *(const bf16x8*)(arow + 32 * ks + 8 * q);
    }

    __syncthreads();

    f32x4 acc[8];
    #pragma unroll
    for (int c = 0; c < 8; ++c) acc[c] = (f32x4){0.f, 0.f, 0.f, 0.f};

    #pragma unroll
    for (int ks = 0; ks < 4; ++ks) {
        int k8 = ks * 4 + q;
        #pragma unroll
        for (int c = 0; c < 8; ++c) {
            int n = c * 16 + m;
            bf16x8 bfrag = *(const bf16x8*)(wt + n * 128 + ((k8 ^ m) << 3));
            acc[c] = __builtin_amdgcn_mfma_f32_16x16x32_bf16(afrag[ks], bfrag, acc[c], 0, 0, 0);
        }
    }

    float bcol[8];
    #pragma unroll
    for (int c = 0; c < 8; ++c) bcol[c] = bias[c * 16 + m];

    #pragma unroll
    for (int r = 0; r < 4; ++r) {
        int nn = n0 + w * 16 + q * 4 + r;
        bool ok = (nn < N_NODES);
        float v[8];
        #pragma unroll
        for (int c = 0; c < 8; ++c) v[c] = acc[c][r] + bcol[c];

        if (ok) {
            #pragma unroll
            for (int c = 0; c < 8; ++c) {
                int col = c * 16 + m;
                if (BF16_OUT) Yb[(size_t)nn * DIM + col] = f2bf(v[c]);
                else          Yf[(size_t)nn * DIM + col] = v[c];
            }
        }

        if (DO_SCORES) {
            float ps[16];
            #pragma unroll
            for (int h = 0; h < 8; ++h) {
                float a = 0.f, b = 0.f;
                #pragma unroll
                for (int c = 0; c < 8; ++c) {
                    int col = c * 16 + m;
                    a += v[c] * wuvT[0][h * 128 + col];
                    b += v[c] * wuvT[1][h * 128 + col];
                }
                ps[h] = a; ps[8 + h] = b;
            }
            #pragma unroll
            for (int o = 1; o < 16; o <<= 1) {
                #pragma unroll
                for (int j = 0; j < 16; ++j) ps[j] += __shfl_xor(ps[j], o);
            }
            if (ok) {
                if (m < 8) su[nn * H + m] = ps[m] + b_u[m];
                else       sv[nn * H + (m - 8)] = ps[m];
            }
        }
    }
}

// ---------------------------------------------------------------------------
// Counting-sort pass 1 (unchanged): partition edges by dst/PART_NODES.
// ---------------------------------------------------------------------------
__global__ __launch_bounds__(256) void k_part(
    const int* __restrict__ src, const int* __restrict__ dst,
    int* __restrict__ pcount, uint_t* __restrict__ pbuf)
{
    __shared__ int hist[NPART];
    __shared__ int base[NPART];
    __shared__ uint_t rec[EPB];
    __shared__ ushort_t rnk[EPB];
    __shared__ unsigned char prt[EPB];

    const int t = threadIdx.x;
    const int e0 = blockIdx.x * EPB;
    hist[t] = 0;
    __syncthreads();

    #pragma unroll
    for (int i = 0; i < EPB / 256; ++i) {
        int idx = i * 256 + t;
        int e = e0 + idx;
        if (e < N_EDGES) {
            int s = src[e], d = dst[e];
            int p = d / PART_NODES;
            int dl = d - p * PART_NODES;
            int r = atomicAdd(&hist[p], 1);
            rec[idx] = ((uint_t)dl << 16) | (uint_t)s;
            rnk[idx] = (ushort_t)r;
            prt[idx] = (unsigned char)p;
        }
    }
    __syncthreads();
    base[t] = atomicAdd(&pcount[t], hist[t]);
    __syncthreads();

    #pragma unroll
    for (int i = 0; i < EPB / 256; ++i) {
        int idx = i * 256 + t;
        int e = e0 + idx;
        if (e < N_EDGES) {
            int p = prt[idx];
            int slot = base[p] + (int)rnk[idx];
            if (slot < PART_CAP)
                pbuf[(size_t)p * PART_CAP + slot] = rec[idx];
        }
    }
}

// ---------------------------------------------------------------------------
// Counting-sort pass 2 (unchanged): LDS bucket per partition, coalesced dump.
// ---------------------------------------------------------------------------
__global__ __launch_bounds__(256) void k_bucket(
    const uint_t* __restrict__ pbuf, const int* __restrict__ pcount,
    ushort_t* __restrict__ esrc_p, int* __restrict__ deg)
{
    __shared__ ushort_t buck[PART_NODES * PAD];   // 25088 B
    __shared__ int cnt[PART_NODES];

    const int p = blockIdx.x, t = threadIdx.x;
    for (int i = t; i < PART_NODES; i += 256) cnt[i] = 0;
    __syncthreads();

    const int m = min(pcount[p], PART_CAP);
    for (int i = t; i < m; i += 256) {
        uint_t v = pbuf[(size_t)p * PART_CAP + i];
        int dl = (int)(v >> 16);
        int pos = atomicAdd(&cnt[dl], 1);
        if (pos < PAD) buck[dl * PAD + pos] = (ushort_t)(v & 0xFFFF);
    }
    __syncthreads();

    const int n0 = p * PART_NODES;
    const uint_t* b32 = (const uint_t*)buck;
    uint_t* g32 = (uint_t*)(esrc_p + (size_t)n0 * PAD);
    for (int i = t; i < PART_NODES * PAD / 2; i += 256) g32[i] = b32[i];
    for (int i = t; i < PART_NODES; i += 256) {
        int n = n0 + i;
        if (n < N_NODES) deg[n] = cnt[i];
    }
}

// ---------------------------------------------------------------------------
// Softmax + aggregation, two-phase:
//  A: lane i computes the 8 head-weights of edge i ONCE (8d exps instead of
//     128d), stores to LDS w[i][h].
//  B: edge loop reads weight pair via broadcast ds_read_b64 (LDS pipe, no
//     VALU), gathers y dword, 2 FMA + 2 add + 2 one-op bf16 unpacks.
// 2 nodes per 128-thr block; lane l owns features 2l,2l+1 (heads 2(l&3)+0,1).
// No max subtraction (|e|<=~10, fp32-safe). deg-0 -> 0.
// ---------------------------------------------------------------------------
__global__ __launch_bounds__(128) void k_node_agg(
    const ushort_t* __restrict__ esrc_p, const int* __restrict__ deg,
    const float* __restrict__ su, const float* __restrict__ sv,
    const ushort_t* __restrict__ yb, ushort_t* __restrict__ aggb)
{
    __shared__ float wls[2][PAD * 8];   // 4 KB: per node, w[edge][head]

    const int w = threadIdx.x >> 6, l = threadIdx.x & 63;
    const int n = blockIdx.x * 2 + w;
    const int d = min(deg[n], PAD);
    const int sl = (l < d) ? (int)esrc_p[(size_t)n * PAD + l] : 0;

    // ---- Phase A
    if (l < d) {
        float4 sva = *(const float4*)(sv + n * H);
        float4 svb = *(const float4*)(sv + n * H + 4);
        float4 sua = *(const float4*)(su + sl * H);
        float4 sub = *(const float4*)(su + sl * H + 4);
        float e[8] = {sua.x+sva.x, sua.y+sva.y, sua.z+sva.z, sua.w+sva.w,
                      sub.x+svb.x, sub.y+svb.y, sub.z+svb.z, sub.w+svb.w};
        float wv[8];
        #pragma unroll
        for (int h = 0; h < 8; ++h) {
            float ee = e[h];
            ee = (ee >= 0.f) ? ee : 0.2f * ee;
            wv[h] = __expf(ee);
        }
        *(float4*)(&wls[w][l * 8])     = make_float4(wv[0], wv[1], wv[2], wv[3]);
        *(float4*)(&wls[w][l * 8 + 4]) = make_float4(wv[4], wv[5], wv[6], wv[7]);
    }
    __syncthreads();

    // ---- Phase B
    const float* wrow = &wls[w][2 * (l & 3)];
    float ssum0 = 0.f, ssum1 = 0.f, acc0 = 0.f, acc1 = 0.f;
    int i = 0;
    for (; i + 4 <= d; i += 4) {
        int s0 = __shfl(sl, i);
        int s1 = __shfl(sl, i + 1);
        int s2 = __shfl(sl, i + 2);
        int s3 = __shfl(sl, i + 3);
        float2 w0 = *(const float2*)(wrow + (i    ) * 8);
        float2 w1 = *(const float2*)(wrow + (i + 1) * 8);
        float2 w2 = *(const float2*)(wrow + (i + 2) * 8);
        float2 w3 = *(const float2*)(wrow + (i + 3) * 8);
        uint_t y0 = *(const uint_t*)(yb + (size_t)s0 * DIM + 2 * l);
        uint_t y1 = *(const uint_t*)(yb + (size_t)s1 * DIM + 2 * l);
        uint_t y2 = *(const uint_t*)(yb + (size_t)s2 * DIM + 2 * l);
        uint_t y3 = *(const uint_t*)(yb + (size_t)s3 * DIM + 2 * l);

        ssum0 += (w0.x + w1.x) + (w2.x + w3.x);
        ssum1 += (w0.y + w1.y) + (w2.y + w3.y);
        acc0 += w0.x * __uint_as_float(y0 << 16) + w1.x * __uint_as_float(y1 << 16)
              + w2.x * __uint_as_float(y2 << 16) + w3.x * __uint_as_float(y3 << 16);
        acc1 += w0.y * __uint_as_float(y0 & 0xFFFF0000u) + w1.y * __uint_as_float(y1 & 0xFFFF0000u)
              + w2.y * __uint_as_float(y2 & 0xFFFF0000u) + w3.y * __uint_as_float(y3 & 0xFFFF0000u);
    }
    for (; i < d; ++i) {
        int s0 = __shfl(sl, i);
        float2 w0 = *(const float2*)(wrow + i * 8);
        uint_t y0 = *(const uint_t*)(yb + (size_t)s0 * DIM + 2 * l);
        ssum0 += w0.x; ssum1 += w0.y;
        acc0 += w0.x * __uint_as_float(y0 << 16);
        acc1 += w0.y * __uint_as_float(y0 & 0xFFFF0000u);
    }
    float r0 = (ssum0 > 0.f) ? (1.0f / ssum0) : 0.f;
    float r1 = (ssum1 > 0.f) ? (1.0f / ssum1) : 0.f;
    uint_t o = (uint_t)f2bf(acc0 * r0) | ((uint_t)f2bf(acc1 * r1) << 16);
    *(uint_t*)(aggb + (size_t)n * DIM + 2 * l) = o;
}

// ---------------------------------------------------------------------------
extern "C" void kernel_launch(void* const* d_in, const int* in_sizes, int n_in,
                              void* d_out, int out_size, void* d_ws, size_t ws_size,
                              hipStream_t stream)
{
    const float* x     = (const float*)d_in[0];
    const int*   src   = (const int*)  d_in[1];
    const int*   dst   = (const int*)  d_in[2];
    const float* gamma = (const float*)d_in[3];
    const float* beta  = (const float*)d_in[4];
    const float* W_in  = (const float*)d_in[5];
    const float* b_in  = (const float*)d_in[6];
    const float* W_u   = (const float*)d_in[7];
    const float* b_u   = (const float*)d_in[8];
    const float* W_v   = (const float*)d_in[9];
    const float* W_ff  = (const float*)d_in[10];
    const float* b_ff  = (const float*)d_in[11];
    float* out = (float*)d_out;

    char* ws = (char*)d_ws;
    ushort_t* yb     = (ushort_t*)ws; ws += (size_t)N_NODES * DIM * 2;
    ushort_t* aggb   = (ushort_t*)ws; ws += (size_t)N_NODES * DIM * 2;
    float* su        = (float*)ws; ws += (size_t)N_NODES * H * 4;
    float* sv        = (float*)ws; ws += (size_t)N_NODES * H * 4;
    int*   deg       = (int*)  ws; ws += (size_t)N_NODES * 4;
    int*   pcount    = (int*)  ws; ws += (size_t)NPART * 4;
    uint_t* pbuf     = (uint_t*)ws; ws += (size_t)NPART * PART_CAP * 4;
    ushort_t* esrc_p = (ushort_t*)ws; ws += (size_t)NPART * PART_NODES * PAD * 2;

    const int NB_PART = (N_EDGES + EPB - 1) / EPB;   // 391
    const int NB_GEMM = (N_NODES + 63) / 64;         // 782

    hipLaunchKernelGGL((k_gemm_mfma<true, true, true>), dim3(NB_GEMM), dim3(256), 0, stream,
                       x, (const ushort_t*)nullptr, W_in, b_in, gamma, beta,
                       W_u, b_u, W_v,
                       (float*)nullptr, yb, su, sv, pcount);
    hipLaunchKernelGGL(k_part, dim3(NB_PART), dim3(256), 0, stream,
                       src, dst, pcount, pbuf);
    hipLaunchKernelGGL(k_bucket, dim3(NPART), dim3(256), 0, stream,
                       pbuf, pcount, esrc_p, deg);
    hipLaunchKernelGGL(k_node_agg, dim3(N_NODES / 2), dim3(128), 0, stream,
                       esrc_p, deg, su, sv, yb, aggb);
    hipLaunchKernelGGL((k_gemm_mfma<false, false, false>), dim3(NB_GEMM), dim3(256), 0, stream,
                       (const float*)nullptr, aggb, W_ff, b_ff,
                       (const float*)nullptr, (const float*)nullptr,
                       (const float*)nullptr, (const float*)nullptr, (const float*)nullptr,
                       out, (ushort_t*)nullptr, (float*)nullptr, (float*)nullptr,
                       (int*)nullptr);
}

// Round 11
// 194.792 us; speedup vs baseline: 6.8154x; 1.0651x over previous
//
#include <hip/hip_runtime.h>

#define N_NODES 50000
#define N_EDGES 800000
#define DIM 128
#define H 8
#define PAD 64          // max stored in-degree; deg~Poisson(16), P(>64)~1e-21. Guarded.
#define NPART 256       // dst partitions
#define PART_NODES 196  // ceil(50000/256); NPART*PART_NODES = 50176
#define PART_CAP 4096   // entries per partition region (mean 3125, +17 sigma)
#define EPB 2048        // edges per k_part block

typedef unsigned short ushort_t;
typedef unsigned int uint_t;
typedef __attribute__((ext_vector_type(8))) short bf16x8;
typedef __attribute__((ext_vector_type(4))) float f32x4;

__device__ __forceinline__ float bf2f(ushort_t u) {
    return __uint_as_float(((uint_t)u) << 16);
}
__device__ __forceinline__ ushort_t f2bf(float f) {
    uint_t x = __float_as_uint(f);
    uint_t r = (x + 0x7FFFu + ((x >> 16) & 1u)) >> 16;   // RNE
    return (ushort_t)r;
}

// ---------------------------------------------------------------------------
// One-time W transpose + SPLIT bf16 convert: Thi[n][k] = bf16(W[k][n]),
// Tlo[n][k] = bf16(W[k][n] - Thi). hi+lo carries ~16 mantissa bits -> the
// GEMM's W-quantization error term (~0.004 RMS, x2 GEMMs) vanishes.
// 16 blocks (8 per matrix, 16 n-rows each).
// ---------------------------------------------------------------------------
__global__ __launch_bounds__(256) void k_wtrans(
    const float* __restrict__ Wa, const float* __restrict__ Wb,
    ushort_t* __restrict__ Tahi, ushort_t* __restrict__ Talo,
    ushort_t* __restrict__ Tbhi, ushort_t* __restrict__ Tblo)
{
    __shared__ ushort_t th[16 * 136];
    __shared__ ushort_t tl[16 * 136];
    const int b = blockIdx.x, t = threadIdx.x;
    const float* Win = (b < 8) ? Wa : Wb;
    ushort_t* Thi = (b < 8) ? Tahi : Tbhi;
    ushort_t* Tlo = (b < 8) ? Talo : Tblo;
    const int n0 = (b & 7) * 16;

    #pragma unroll
    for (int rep = 0; rep < 2; ++rep) {
        int k = rep * 64 + (t >> 2);
        int c = (t & 3) * 4;
        float4 v = *(const float4*)(Win + (size_t)k * DIM + n0 + c);
        float vv[4] = {v.x, v.y, v.z, v.w};
        #pragma unroll
        for (int j = 0; j < 4; ++j) {
            ushort_t hi = f2bf(vv[j]);
            ushort_t lo = f2bf(vv[j] - bf2f(hi));
            th[(c + j) * 136 + k] = hi;
            tl[(c + j) * 136 + k] = lo;
        }
    }
    __syncthreads();
    {
        int j = t >> 4;          // 0..15
        int c = (t & 15) * 8;    // 0..120
        *(bf16x8*)(Thi + (size_t)(n0 + j) * DIM + c) = *(const bf16x8*)(th + j * 136 + c);
        *(bf16x8*)(Tlo + (size_t)(n0 + j) * DIM + c) = *(const bf16x8*)(tl + j * 136 + c);
    }
}

// ---------------------------------------------------------------------------
// MFMA GEMM, split-W: Y[n][c] = sum_k A[n][k]*(Whi+Wlo)[k][c] + bias[c].
// Whi/Wlo are pre-transposed bf16 ([c][k] n-major). K staged in two 64-k
// halves: per half, hi+lo tiles (16 KB each) with XOR swizzle
//   wh[n*64 + ((kb ^ (n&7))<<3) + j],  kb = local k-chunk 0..7
// Staging: pure coalesced b128 copies, conflict-free LDS writes (8
// consecutive lanes cover one full 128 B row). B-frag reads: 2-way (free).
// acc = mfma(a, hi, mfma(a, lo, acc)) -> 64 MFMAs/wave.
// A-frag (16x16x32): m=lane&15, k=(lane>>4)*8+j. C/D: col=lane&15, row=q*4+reg.
// DO_SCORES fuses su/sv epilogue and zeroes pcount (block 0).
// ---------------------------------------------------------------------------
template<bool DO_LN, bool BF16_OUT, bool DO_SCORES>
__global__ __launch_bounds__(256) void k_gemm_mfma(
    const float* __restrict__ X, const ushort_t* __restrict__ Ab,
    const ushort_t* __restrict__ Whi, const ushort_t* __restrict__ Wlo,
    const float* __restrict__ bias,
    const float* __restrict__ gamma, const float* __restrict__ beta,
    const float* __restrict__ W_u, const float* __restrict__ b_u,
    const float* __restrict__ W_v,
    float* __restrict__ Yf, ushort_t* __restrict__ Yb,
    float* __restrict__ su, float* __restrict__ sv,
    int* __restrict__ pcount)
{
    __shared__ ushort_t wh[128 * 64];      // 16 KB: hi tile, one 64-k half
    __shared__ ushort_t wl[128 * 64];      // 16 KB: lo tile
    __shared__ float    wuvT[2][8 * 128];  // 8 KB: [0]=W_u^T [h][col], [1]=W_v^T

    const int t  = threadIdx.x;
    const int n0 = blockIdx.x * 64;
    const int l  = t & 63, w = t >> 6;
    const int m  = l & 15, q = l >> 4;

    if (DO_SCORES && blockIdx.x == 0) pcount[t] = 0;   // t<256 == NPART

    if (DO_SCORES) {
        #pragma unroll
        for (int i = 0; i < 8; ++i) {
            int g = i * 256 + t;
            int sel = g >> 10;
            int rem = g & 1023;
            int col = rem >> 3, h = rem & 7;
            float v = sel ? W_v[rem] : W_u[rem];
            wuvT[sel][h * 128 + col] = v;
        }
    }

    // ---- Build A-fragments (no LDS dependency)
    const int node = n0 + w * 16 + m;
    const int nc   = (node < N_NODES) ? node : (N_NODES - 1);
    bf16x8 afrag[4];

    if (DO_LN) {
        const float* xrow = X + (size_t)nc * DIM;
        float xv[4][8];
        float s = 0.f, ss = 0.f;
        #pragma unroll
        for (int ks = 0; ks < 4; ++ks) {
            int base = 32 * ks + 8 * q;
            float4 a0 = *(const float4*)(xrow + base);
            float4 a1 = *(const float4*)(xrow + base + 4);
            xv[ks][0]=a0.x; xv[ks][1]=a0.y; xv[ks][2]=a0.z; xv[ks][3]=a0.w;
            xv[ks][4]=a1.x; xv[ks][5]=a1.y; xv[ks][6]=a1.z; xv[ks][7]=a1.w;
            #pragma unroll
            for (int j = 0; j < 8; ++j) { s += xv[ks][j]; ss += xv[ks][j]*xv[ks][j]; }
        }
        s  += __shfl_xor(s, 16);  s  += __shfl_xor(s, 32);
        ss += __shfl_xor(ss, 16); ss += __shfl_xor(ss, 32);
        float mu   = s * (1.f / DIM);
        float var  = ss * (1.f / DIM) - mu * mu;
        float rstd = rsqrtf(var + 1e-5f);
        #pragma unroll
        for (int ks = 0; ks < 4; ++ks) {
            int base = 32 * ks + 8 * q;
            float4 g0 = *(const float4*)(gamma + base);
            float4 g1 = *(const float4*)(gamma + base + 4);
            float4 b0 = *(const float4*)(beta + base);
            float4 b1 = *(const float4*)(beta + base + 4);
            float gg[8] = {g0.x,g0.y,g0.z,g0.w,g1.x,g1.y,g1.z,g1.w};
            float bb[8] = {b0.x,b0.y,b0.z,b0.w,b1.x,b1.y,b1.z,b1.w};
            #pragma unroll
            for (int j = 0; j < 8; ++j) {
                float xn = (xv[ks][j] - mu) * rstd * gg[j] + bb[j];
                afrag[ks][j] = (short)f2bf(xn);
            }
        }
    } else {
        const ushort_t* arow = Ab + (size_t)nc * DIM;
        #pragma unroll
        for (int ks = 0; ks < 4; ++ks)
            afrag[ks] = *(const bf16x8*)(arow + 32 * ks + 8 * q);
    }

    // ---- MFMA main: 2 k-halves x (stage hi+lo, 2 k-steps x 8 col-tiles x 2)
    f32x4 acc[8];
    #pragma unroll
    for (int c = 0; c < 8; ++c) acc[c] = (f32x4){0.f, 0.f, 0.f, 0.f};

    for (int kc = 0; kc < 2; ++kc) {
        __syncthreads();   // prior-half reads done (first: A/wuvT staging fence)
        #pragma unroll
        for (int rep = 0; rep < 4; ++rep) {
            int id = rep * 256 + t;          // 0..1023
            int n  = id >> 3;                // 0..127
            int kb = id & 7;                 // 0..7 (local 8-k chunk)
            size_t goff = (size_t)n * DIM + kc * 64 + kb * 8;
            int loff = n * 64 + ((kb ^ (n & 7)) << 3);
            *(bf16x8*)(wh + loff) = *(const bf16x8*)(Whi + goff);
            *(bf16x8*)(wl + loff) = *(const bf16x8*)(Wlo + goff);
        }
        __syncthreads();

        #pragma unroll
        for (int ks2 = 0; ks2 < 2; ++ks2) {
            bf16x8 afr = afrag[kc * 2 + ks2];
            int sb = ks2 * 4 + q;            // local k-chunk of this lane's B-frag
            #pragma unroll
            for (int c = 0; c < 8; ++c) {
                int n = c * 16 + m;
                int loff = n * 64 + ((sb ^ (n & 7)) << 3);
                bf16x8 blo = *(const bf16x8*)(wl + loff);
                bf16x8 bhi = *(const bf16x8*)(wh + loff);
                acc[c] = __builtin_amdgcn_mfma_f32_16x16x32_bf16(afr, blo, acc[c], 0, 0, 0);
                acc[c] = __builtin_amdgcn_mfma_f32_16x16x32_bf16(afr, bhi, acc[c], 0, 0, 0);
            }
        }
    }

    // ---- Epilogue: per r, node nn = n0 + w*16 + q*4 + r; col = c*16 + m
    float bcol[8];
    #pragma unroll
    for (int c = 0; c < 8; ++c) bcol[c] = bias[c * 16 + m];

    #pragma unroll
    for (int r = 0; r < 4; ++r) {
        int nn = n0 + w * 16 + q * 4 + r;
        bool ok = (nn < N_NODES);
        float v[8];
        #pragma unroll
        for (int c = 0; c < 8; ++c) v[c] = acc[c][r] + bcol[c];

        if (ok) {
            #pragma unroll
            for (int c = 0; c < 8; ++c) {
                int col = c * 16 + m;
                if (BF16_OUT) Yb[(size_t)nn * DIM + col] = f2bf(v[c]);
                else          Yf[(size_t)nn * DIM + col] = v[c];
            }
        }

        if (DO_SCORES) {
            float ps[16];
            #pragma unroll
            for (int h = 0; h < 8; ++h) {
                float a = 0.f, b = 0.f;
                #pragma unroll
                for (int c = 0; c < 8; ++c) {
                    int col = c * 16 + m;
                    a += v[c] * wuvT[0][h * 128 + col];
                    b += v[c] * wuvT[1][h * 128 + col];
                }
                ps[h] = a; ps[8 + h] = b;
            }
            #pragma unroll
            for (int o = 1; o < 16; o <<= 1) {
                #pragma unroll
                for (int j = 0; j < 16; ++j) ps[j] += __shfl_xor(ps[j], o);
            }
            if (ok) {
                if (m < 8) su[nn * H + m] = ps[m] + b_u[m];
                else       sv[nn * H + (m - 8)] = ps[m];
            }
        }
    }
}

// ---------------------------------------------------------------------------
// Counting-sort pass 1 (unchanged): partition edges by dst/PART_NODES.
// ---------------------------------------------------------------------------
__global__ __launch_bounds__(256) void k_part(
    const int* __restrict__ src, const int* __restrict__ dst,
    int* __restrict__ pcount, uint_t* __restrict__ pbuf)
{
    __shared__ int hist[NPART];
    __shared__ int base[NPART];
    __shared__ uint_t rec[EPB];
    __shared__ ushort_t rnk[EPB];
    __shared__ unsigned char prt[EPB];

    const int t = threadIdx.x;
    const int e0 = blockIdx.x * EPB;
    hist[t] = 0;
    __syncthreads();

    #pragma unroll
    for (int i = 0; i < EPB / 256; ++i) {
        int idx = i * 256 + t;
        int e = e0 + idx;
        if (e < N_EDGES) {
            int s = src[e], d = dst[e];
            int p = d / PART_NODES;
            int dl = d - p * PART_NODES;
            int r = atomicAdd(&hist[p], 1);
            rec[idx] = ((uint_t)dl << 16) | (uint_t)s;
            rnk[idx] = (ushort_t)r;
            prt[idx] = (unsigned char)p;
        }
    }
    __syncthreads();
    base[t] = atomicAdd(&pcount[t], hist[t]);
    __syncthreads();

    #pragma unroll
    for (int i = 0; i < EPB / 256; ++i) {
        int idx = i * 256 + t;
        int e = e0 + idx;
        if (e < N_EDGES) {
            int p = prt[idx];
            int slot = base[p] + (int)rnk[idx];
            if (slot < PART_CAP)
                pbuf[(size_t)p * PART_CAP + slot] = rec[idx];
        }
    }
}

// ---------------------------------------------------------------------------
// Counting-sort pass 2 (unchanged): LDS bucket per partition, coalesced dump.
// ---------------------------------------------------------------------------
__global__ __launch_bounds__(256) void k_bucket(
    const uint_t* __restrict__ pbuf, const int* __restrict__ pcount,
    ushort_t* __restrict__ esrc_p, int* __restrict__ deg)
{
    __shared__ ushort_t buck[PART_NODES * PAD];   // 25088 B
    __shared__ int cnt[PART_NODES];

    const int p = blockIdx.x, t = threadIdx.x;
    for (int i = t; i < PART_NODES; i += 256) cnt[i] = 0;
    __syncthreads();

    const int m = min(pcount[p], PART_CAP);
    for (int i = t; i < m; i += 256) {
        uint_t v = pbuf[(size_t)p * PART_CAP + i];
        int dl = (int)(v >> 16);
        int pos = atomicAdd(&cnt[dl], 1);
        if (pos < PAD) buck[dl * PAD + pos] = (ushort_t)(v & 0xFFFF);
    }
    __syncthreads();

    const int n0 = p * PART_NODES;
    const uint_t* b32 = (const uint_t*)buck;
    uint_t* g32 = (uint_t*)(esrc_p + (size_t)n0 * PAD);
    for (int i = t; i < PART_NODES * PAD / 2; i += 256) g32[i] = b32[i];
    for (int i = t; i < PART_NODES; i += 256) {
        int n = n0 + i;
        if (n < N_NODES) deg[n] = cnt[i];
    }
}

// ---------------------------------------------------------------------------
// Softmax + aggregation, two-phase (unchanged from R8): Phase A computes each
// edge's 8 head-weights once into LDS; Phase B is LDS-broadcast + FMA loop.
// ---------------------------------------------------------------------------
__global__ __launch_bounds__(128) void k_node_agg(
    const ushort_t* __restrict__ esrc_p, const int* __restrict__ deg,
    const float* __restrict__ su, const float* __restrict__ sv,
    const ushort_t* __restrict__ yb, ushort_t* __restrict__ aggb)
{
    __shared__ float wls[2][PAD * 8];   // 4 KB: per node, w[edge][head]

    const int w = threadIdx.x >> 6, l = threadIdx.x & 63;
    const int n = blockIdx.x * 2 + w;
    const int d = min(deg[n], PAD);
    const int sl = (l < d) ? (int)esrc_p[(size_t)n * PAD + l] : 0;

    if (l < d) {
        float4 sva = *(const float4*)(sv + n * H);
        float4 svb = *(const float4*)(sv + n * H + 4);
        float4 sua = *(const float4*)(su + sl * H);
        float4 sub = *(const float4*)(su + sl * H + 4);
        float e[8] = {sua.x+sva.x, sua.y+sva.y, sua.z+sva.z, sua.w+sva.w,
                      sub.x+svb.x, sub.y+svb.y, sub.z+svb.z, sub.w+svb.w};
        float wv[8];
        #pragma unroll
        for (int h = 0; h < 8; ++h) {
            float ee = e[h];
            ee = (ee >= 0.f) ? ee : 0.2f * ee;
            wv[h] = __expf(ee);
        }
        *(float4*)(&wls[w][l * 8])     = make_float4(wv[0], wv[1], wv[2], wv[3]);
        *(float4*)(&wls[w][l * 8 + 4]) = make_float4(wv[4], wv[5], wv[6], wv[7]);
    }
    __syncthreads();

    const float* wrow = &wls[w][2 * (l & 3)];
    float ssum0 = 0.f, ssum1 = 0.f, acc0 = 0.f, acc1 = 0.f;
    int i = 0;
    for (; i + 4 <= d; i += 4) {
        int s0 = __shfl(sl, i);
        int s1 = __shfl(sl, i + 1);
        int s2 = __shfl(sl, i + 2);
        int s3 = __shfl(sl, i + 3);
        float2 w0 = *(const float2*)(wrow + (i    ) * 8);
        float2 w1 = *(const float2*)(wrow + (i + 1) * 8);
        float2 w2 = *(const float2*)(wrow + (i + 2) * 8);
        float2 w3 = *(const float2*)(wrow + (i + 3) * 8);
        uint_t y0 = *(const uint_t*)(yb + (size_t)s0 * DIM + 2 * l);
        uint_t y1 = *(const uint_t*)(yb + (size_t)s1 * DIM + 2 * l);
        uint_t y2 = *(const uint_t*)(yb + (size_t)s2 * DIM + 2 * l);
        uint_t y3 = *(const uint_t*)(yb + (size_t)s3 * DIM + 2 * l);

        ssum0 += (w0.x + w1.x) + (w2.x + w3.x);
        ssum1 += (w0.y + w1.y) + (w2.y + w3.y);
        acc0 += w0.x * __uint_as_float(y0 << 16) + w1.x * __uint_as_float(y1 << 16)
              + w2.x * __uint_as_float(y2 << 16) + w3.x * __uint_as_float(y3 << 16);
        acc1 += w0.y * __uint_as_float(y0 & 0xFFFF0000u) + w1.y * __uint_as_float(y1 & 0xFFFF0000u)
              + w2.y * __uint_as_float(y2 & 0xFFFF0000u) + w3.y * __uint_as_float(y3 & 0xFFFF0000u);
    }
    for (; i < d; ++i) {
        int s0 = __shfl(sl, i);
        float2 w0 = *(const float2*)(wrow + i * 8);
        uint_t y0 = *(const uint_t*)(yb + (size_t)s0 * DIM + 2 * l);
        ssum0 += w0.x; ssum1 += w0.y;
        acc0 += w0.x * __uint_as_float(y0 << 16);
        acc1 += w0.y * __uint_as_float(y0 & 0xFFFF0000u);
    }
    float r0 = (ssum0 > 0.f) ? (1.0f / ssum0) : 0.f;
    float r1 = (ssum1 > 0.f) ? (1.0f / ssum1) : 0.f;
    uint_t o = (uint_t)f2bf(acc0 * r0) | ((uint_t)f2bf(acc1 * r1) << 16);
    *(uint_t*)(aggb + (size_t)n * DIM + 2 * l) = o;
}

// ---------------------------------------------------------------------------
extern "C" void kernel_launch(void* const* d_in, const int* in_sizes, int n_in,
                              void* d_out, int out_size, void* d_ws, size_t ws_size,
                              hipStream_t stream)
{
    const float* x     = (const float*)d_in[0];
    const int*   src   = (const int*)  d_in[1];
    const int*   dst   = (const int*)  d_in[2];
    const float* gamma = (const float*)d_in[3];
    const float* beta  = (const float*)d_in[4];
    const float* W_in  = (const float*)d_in[5];
    const float* b_in  = (const float*)d_in[6];
    const float* W_u   = (const float*)d_in[7];
    const float* b_u   = (const float*)d_in[8];
    const float* W_v   = (const float*)d_in[9];
    const float* W_ff  = (const float*)d_in[10];
    const float* b_ff  = (const float*)d_in[11];
    float* out = (float*)d_out;

    char* ws = (char*)d_ws;
    ushort_t* yb     = (ushort_t*)ws; ws += (size_t)N_NODES * DIM * 2;
    ushort_t* aggb   = (ushort_t*)ws; ws += (size_t)N_NODES * DIM * 2;
    float* su        = (float*)ws; ws += (size_t)N_NODES * H * 4;
    float* sv        = (float*)ws; ws += (size_t)N_NODES * H * 4;
    int*   deg       = (int*)  ws; ws += (size_t)N_NODES * 4;
    int*   pcount    = (int*)  ws; ws += (size_t)NPART * 4;
    uint_t* pbuf     = (uint_t*)ws; ws += (size_t)NPART * PART_CAP * 4;
    ushort_t* esrc_p = (ushort_t*)ws; ws += (size_t)NPART * PART_NODES * PAD * 2;
    ushort_t* wt_in_hi = (ushort_t*)ws; ws += (size_t)DIM * DIM * 2;
    ushort_t* wt_in_lo = (ushort_t*)ws; ws += (size_t)DIM * DIM * 2;
    ushort_t* wt_ff_hi = (ushort_t*)ws; ws += (size_t)DIM * DIM * 2;
    ushort_t* wt_ff_lo = (ushort_t*)ws; ws += (size_t)DIM * DIM * 2;

    const int NB_PART = (N_EDGES + EPB - 1) / EPB;   // 391
    const int NB_GEMM = (N_NODES + 63) / 64;         // 782

    hipLaunchKernelGGL(k_wtrans, dim3(16), dim3(256), 0, stream,
                       W_in, W_ff, wt_in_hi, wt_in_lo, wt_ff_hi, wt_ff_lo);
    hipLaunchKernelGGL((k_gemm_mfma<true, true, true>), dim3(NB_GEMM), dim3(256), 0, stream,
                       x, (const ushort_t*)nullptr, wt_in_hi, wt_in_lo, b_in, gamma, beta,
                       W_u, b_u, W_v,
                       (float*)nullptr, yb, su, sv, pcount);
    hipLaunchKernelGGL(k_part, dim3(NB_PART), dim3(256), 0, stream,
                       src, dst, pcount, pbuf);
    hipLaunchKernelGGL(k_bucket, dim3(NPART), dim3(256), 0, stream,
                       pbuf, pcount, esrc_p, deg);
    hipLaunchKernelGGL(k_node_agg, dim3(N_NODES / 2), dim3(128), 0, stream,
                       esrc_p, deg, su, sv, yb, aggb);
    hipLaunchKernelGGL((k_gemm_mfma<false, false, false>), dim3(NB_GEMM), dim3(256), 0, stream,
                       (const float*)nullptr, aggb, wt_ff_hi, wt_ff_lo, b_ff,
                       (const float*)nullptr, (const float*)nullptr,
                       (const float*)nullptr, (const float*)nullptr, (const float*)nullptr,
                       out, (ushort_t*)nullptr, (float*)nullptr, (float*)nullptr,
                       (int*)nullptr);
}